// Round 7
// baseline (4096.638 us; speedup 1.0000x reference)
//
#include <hip/hip_runtime.h>
#include <hip/hip_cooperative_groups.h>
#include <math.h>

namespace cg = cooperative_groups;

#define B_ 512
#define N_ 20
#define H_ 450
#define L_ 56
#define V_ 780
#define T_ 38
#define NNODES (B_*N_)        // 10240
#define NEDGES (B_*2*(N_-1))  // 19456
#define NPROWS ((T_+1)*B_)    // 19968
#define MAXP 8
#define MAXD 8
#define KS 480                // scan K pad (450 -> 480 = 15*32); also m/rm row stride
#define AST 488               // A-tile LDS row stride in shorts (976B, 16B-aligned, 2-way banks)

typedef __attribute__((ext_vector_type(8))) short bf16x8;
typedef __attribute__((ext_vector_type(4))) float f32x4;

__device__ __forceinline__ float sigmoidf_(float v){ return 1.0f/(1.0f+expf(-v)); }

__device__ __forceinline__ unsigned short f2b(float x){
  unsigned int u = __float_as_uint(x);
  unsigned int r = (u + 0x7fffu + ((u >> 16) & 1u)) >> 16;
  return (unsigned short)r;
}
__device__ __forceinline__ float b2f(unsigned short v){
  return __uint_as_float((unsigned int)v << 16);
}
__device__ __forceinline__ unsigned int pack2(float lo, float hi){
  return (unsigned int)f2b(lo) | ((unsigned int)f2b(hi) << 16);
}

// ---------------------------------------------------------------------------
// xb[i][:] = bf16(emb[wid[i]][:]), K-padded to 480
__global__ __launch_bounds__(256) void k_gather_xb(const float* __restrict__ emb,
    const int* __restrict__ wid, unsigned short* __restrict__ xb){
  int w = blockIdx.x*4 + (threadIdx.x>>6), lane = threadIdx.x & 63;
  if (w >= NNODES) return;
  const float2* src = (const float2*)(emb + (size_t)wid[w]*H_);
  unsigned int* dst = (unsigned int*)(xb + (size_t)w*KS);
  for (int j2 = lane; j2 < 240; j2 += 64){
    unsigned int v = 0;
    if (j2 < 225){ float2 f = src[j2]; v = pack2(f.x, f.y); }
    dst[j2] = v;
  }
}

// Transpose+convert weight to K-major bf16 with zero padding.
__global__ void k_wt(const float* __restrict__ W1, const float* __restrict__ W2,
                     int Ksplit, int Kact, int Nact, unsigned short* __restrict__ dst, int Kpad){
  int c = blockIdx.x;
  unsigned short* drow = dst + (size_t)c*Kpad;
  for (int k = threadIdx.x; k < Kpad; k += blockDim.x){
    float v = 0.f;
    if (c < Nact && k < Kact)
      v = (k < Ksplit) ? W1[(size_t)k*Nact + c] : W2[(size_t)(k-Ksplit)*Nact + c];
    drow[k] = f2b(v);
  }
}

// ---------------------------------------------------------------------------
struct ScanP {
  const unsigned short *WzB, *WhB, *UrT;        // [512][480] K-major bf16 (bottom/Ur)
  const unsigned short *XWz, *XWh, *XWr;        // [10240][450] bf16, bias folded in
  const int *edge_src, *edge_dst, *edge_pred, *node_in, *step_eid, *step_v;
  unsigned short *m, *rm, *hb;                  // m/rm [NEDGES+1][480], hb [T*B][450]
  int P, Dn;
};

// Cooperative scan: 64 blocks = 8 tree-tiles x 8 col-tiles, 1024 thr (16 waves 4x4).
// K-loops have NO barriers: A from LDS, B (and rgate A) direct global->fragment.
__global__ __launch_bounds__(1024,1) void k_scan_coop(ScanP p){
  cg::grid_group grid = cg::this_grid();
  __shared__ unsigned short A1s[64*AST];        // [s]   rows=trees
  __shared__ unsigned short A2s[64*AST];        // [arm]
  __shared__ int s_moff[64], s_src[64], s_dst[64], s_pcnt[64], s_dcnt[64];
  __shared__ int s_poff[64][MAXP];
  __shared__ int s_noff[64][MAXD];

  const int tid = threadIdx.x;
  const int lane = tid & 63, l15 = lane & 15, kh = lane >> 4;
  const int ko = kh*8;
  const int wv = tid >> 6, wr = wv >> 2, wc = wv & 3;
  const int by = blockIdx.x >> 3, bx = blockIdx.x & 7;
  const int r0 = by*64, c0 = bx*64;
  const int P = p.P, Dn = p.Dn;
  const int gr = tid >> 4, gsub = tid & 15;     // gather: 16 threads per tree row
  const int cc = c0 + wc*16 + l15;              // this lane's output column
  const int arow = wr*16 + l15;                 // this lane's A row (tree within block)

  // fixed per-wave B row pointers (K-major panels, L2-resident)
  const unsigned short* pWz = p.WzB + (size_t)cc*KS;
  const unsigned short* pWh = p.WhB + (size_t)cc*KS;
  const unsigned short* pUr = p.UrT + (size_t)cc*KS;
  const unsigned short* aR1 = A1s + arow*AST;
  const unsigned short* aR2 = A2s + arow*AST;

  for (int t = 0; t < T_; ++t){
    if (tid < 64){
      int b = r0 + tid;
      int e = p.step_eid[t*B_ + b];
      s_moff[tid] = e*KS;
      s_src[tid] = p.edge_src[e]*H_;
      s_dst[tid] = p.edge_dst[e]*H_;
      int pc = 0;
      for (int q = 0; q < P; ++q){
        int pe = p.edge_pred[e*P + q];
        if (pe != NEDGES) s_poff[tid][pc++] = pe*KS;
      }
      s_pcnt[tid] = pc;
      int v = p.step_v[t*B_ + b];
      int dc = 0;
      for (int d = 0; d < Dn; ++d){
        int ne = p.node_in[v*Dn + d];
        if (ne != NEDGES) s_noff[tid][dc++] = ne*KS;
      }
      s_dcnt[tid] = dc;
    }
    __syncthreads();                       // metadata ready

    // ---- gather A1=[s], A2=[arm] into LDS (uint2 = 4 bf16 per load) ----
    {
      int pc = s_pcnt[gr];
      uint2* d1 = (uint2*)(A1s + gr*AST);
      uint2* d2 = (uint2*)(A2s + gr*AST);
      for (int j4 = gsub; j4 < 120; j4 += 16){
        float f0=0.f,f1=0.f,f2=0.f,f3=0.f;
        float g0=0.f,g1=0.f,g2=0.f,g3=0.f;
        for (int q = 0; q < pc; ++q){
          int o = s_poff[gr][q] + 4*j4;
          uint2 mv = *(const uint2*)(p.m + o);
          uint2 rv = *(const uint2*)(p.rm + o);
          f0 += b2f((unsigned short)(mv.x & 0xffff)); f1 += b2f((unsigned short)(mv.x >> 16));
          f2 += b2f((unsigned short)(mv.y & 0xffff)); f3 += b2f((unsigned short)(mv.y >> 16));
          g0 += b2f((unsigned short)(rv.x & 0xffff)); g1 += b2f((unsigned short)(rv.x >> 16));
          g2 += b2f((unsigned short)(rv.y & 0xffff)); g3 += b2f((unsigned short)(rv.y >> 16));
        }
        uint2 w1; w1.x = pack2(f0,f1); w1.y = pack2(f2,f3);
        uint2 w2; w2.x = pack2(g0,g1); w2.y = pack2(g2,g3);
        d1[j4] = w1; d2[j4] = w2;
      }
    }
    __syncthreads();                       // A tiles ready

    // ---- gate K-loop: Z = s@WzB, H = arm@WhB (no barriers) ----
    f32x4 accZ = {}, accH = {};
    #pragma unroll
    for (int it = 0; it < 15; ++it){
      bf16x8 a1 = *(const bf16x8*)(aR1 + it*32 + ko);
      bf16x8 a2 = *(const bf16x8*)(aR2 + it*32 + ko);
      bf16x8 b1 = *(const bf16x8*)(pWz + it*32 + ko);
      bf16x8 b2 = *(const bf16x8*)(pWh + it*32 + ko);
      accZ = __builtin_amdgcn_mfma_f32_16x16x32_bf16(a1,b1,accZ,0,0,0);
      accH = __builtin_amdgcn_mfma_f32_16x16x32_bf16(a2,b2,accH,0,0,0);
    }

    // ---- gate epilogue: m[eid] = (1-z)*s + z*tanh(...) (bf16) ----
    if (cc < H_){
      #pragma unroll
      for (int reg = 0; reg < 4; ++reg){
        int rl = wr*16 + kh*4 + reg;
        float z  = sigmoidf_(accZ[reg] + b2f(p.XWz[s_src[rl] + cc]));
        float th = tanhf   (accH[reg] + b2f(p.XWh[s_src[rl] + cc]));
        float s_ = 0.f;
        int pc = s_pcnt[rl];
        for (int q = 0; q < pc; ++q) s_ += b2f(p.m[s_poff[rl][q] + cc]);
        float mn = (1.f - z)*s_ + z*th;
        p.m[s_moff[rl] + cc] = f2b(mn);
      }
    }
    __threadfence();
    grid.sync();   // m_new complete across all col-tiles

    // ---- rgate K-loop: R = m_new@Ur (A rows straight from global m) ----
    {
      const unsigned short* aM = p.m + s_moff[arow];
      f32x4 accR = {};
      #pragma unroll
      for (int it = 0; it < 15; ++it){
        bf16x8 a = *(const bf16x8*)(aM + it*32 + ko);
        bf16x8 b = *(const bf16x8*)(pUr + it*32 + ko);
        accR = __builtin_amdgcn_mfma_f32_16x16x32_bf16(a,b,accR,0,0,0);
      }

      // ---- rgate epilogue: rm, h-pull ----
      if (cc < H_){
        #pragma unroll
        for (int reg = 0; reg < 4; ++reg){
          int rl = wr*16 + kh*4 + reg;
          float r_ = sigmoidf_(accR[reg] + b2f(p.XWr[s_dst[rl] + cc]));
          float mn = b2f(p.m[s_moff[rl] + cc]);
          p.rm[s_moff[rl] + cc] = f2b(r_*mn);
          float h = 0.f;
          int dc = s_dcnt[rl];
          for (int d = 0; d < dc; ++d) h += b2f(p.m[s_noff[rl][d] + cc]);
          p.hb[(size_t)(t*B_ + r0 + rl)*H_ + cc] = f2b(h);
        }
      }
    }
    __threadfence();
    grid.sync();   // rm complete -> next step's gather
  }
}

// ---------------------------------------------------------------------------
// MFMA tile core for heads: 64x64 tile, 4 waves (2x2), BK=32, K-major bf16.
__device__ __forceinline__ void mfma_tile_core(
    const unsigned short* __restrict__ A, const unsigned short* __restrict__ BT,
    int K, int gr0, int gc0, int tid,
    unsigned short* __restrict__ As, unsigned short* __restrict__ Bs,
    f32x4 (&acc)[2][2])
{
  const int lane = tid & 63;
  const int w = tid >> 6, wr = w >> 1, wc = w & 1;
  const int l15 = lane & 15, kh = lane >> 4;
  const int sr = tid >> 2, sj = (tid & 3) * 8;
  const size_t arow = (size_t)(gr0 + sr) * K;
  const size_t brow = (size_t)(gc0 + sr) * K;
  for (int kt = 0; kt < K; kt += 32){
    __syncthreads();
    *(float4*)&As[sr*40 + sj] = *(const float4*)&A[arow + kt + sj];
    *(float4*)&Bs[sr*40 + sj] = *(const float4*)&BT[brow + kt + sj];
    __syncthreads();
    bf16x8 a0 = *(const bf16x8*)&As[(wr*32      + l15)*40 + kh*8];
    bf16x8 a1 = *(const bf16x8*)&As[(wr*32 + 16 + l15)*40 + kh*8];
    bf16x8 b0 = *(const bf16x8*)&Bs[(wc*32      + l15)*40 + kh*8];
    bf16x8 b1 = *(const bf16x8*)&Bs[(wc*32 + 16 + l15)*40 + kh*8];
    acc[0][0] = __builtin_amdgcn_mfma_f32_16x16x32_bf16(a0,b0,acc[0][0],0,0,0);
    acc[0][1] = __builtin_amdgcn_mfma_f32_16x16x32_bf16(a0,b1,acc[0][1],0,0,0);
    acc[1][0] = __builtin_amdgcn_mfma_f32_16x16x32_bf16(a1,b0,acc[1][0],0,0,0);
    acc[1][1] = __builtin_amdgcn_mfma_f32_16x16x32_bf16(a1,b1,acc[1][1],0,0,0);
  }
}

// Head GEMM: C = act(A@B + bias); f32 store and/or bf16 store.
__global__ __launch_bounds__(256) void k_head_mfma(
    const unsigned short* __restrict__ A, const unsigned short* __restrict__ BT, int K,
    const float* __restrict__ bias, int Nact, int relu,
    float* __restrict__ outF, int ldF, unsigned short* __restrict__ outB, int ldB)
{
  __shared__ unsigned short As[64*40], Bs[64*40];
  const int tid = threadIdx.x;
  const int gr0 = blockIdx.y*64, gc0 = blockIdx.x*64;
  f32x4 acc[2][2] = {};
  mfma_tile_core(A, BT, K, gr0, gc0, tid, As, Bs, acc);
  const int lane = tid & 63;
  const int w = tid >> 6, wr = w >> 1, wc = w & 1;
  const int l15 = lane & 15, kh = lane >> 4;
  #pragma unroll
  for (int mi = 0; mi < 2; ++mi){
    #pragma unroll
    for (int n = 0; n < 2; ++n){
      int c = gc0 + wc*32 + n*16 + l15;
      float bc = (c < Nact) ? bias[c] : 0.f;
      #pragma unroll
      for (int reg = 0; reg < 4; ++reg){
        int r = gr0 + wr*32 + mi*16 + kh*4 + reg;
        float v = acc[mi][n][reg] + bc;
        if (relu) v = fmaxf(v, 0.f);
        if (outF && c < Nact) outF[(size_t)r*ldF + c] = v;
        if (outB && c < ldB)  outB[(size_t)r*ldB + c] = (c < Nact) ? f2b(v) : (unsigned short)0;
      }
    }
  }
}

// p-head GEMM with fused Us-dot: plog[r] += sum_c relu(acc+bu)*Us[c]
__global__ __launch_bounds__(256) void k_head_p(
    const unsigned short* __restrict__ A, const unsigned short* __restrict__ BT,
    const float* __restrict__ bu_, const float* __restrict__ Us, float* __restrict__ plog)
{
  __shared__ unsigned short As[64*40], Bs[64*40];
  const int tid = threadIdx.x;
  const int gr0 = blockIdx.y*64, gc0 = blockIdx.x*64;
  f32x4 acc[2][2] = {};
  mfma_tile_core(A, BT, 960, gr0, gc0, tid, As, Bs, acc);
  const int lane = tid & 63;
  const int w = tid >> 6, wr = w >> 1, wc = w & 1;
  const int l15 = lane & 15, kh = lane >> 4;
  #pragma unroll
  for (int mi = 0; mi < 2; ++mi){
    float rowsum[4] = {0.f,0.f,0.f,0.f};
    #pragma unroll
    for (int n = 0; n < 2; ++n){
      int c = gc0 + wc*32 + n*16 + l15;
      float uc = 0.f, bc = 0.f;
      if (c < H_){ uc = Us[c]; bc = bu_[c]; }
      #pragma unroll
      for (int reg = 0; reg < 4; ++reg){
        float v = fmaxf(acc[mi][n][reg] + bc, 0.f);
        rowsum[reg] += (c < H_) ? v*uc : 0.f;
      }
    }
    #pragma unroll
    for (int reg = 0; reg < 4; ++reg){
      float p = rowsum[reg];
      p += __shfl_xor(p,1); p += __shfl_xor(p,2);
      p += __shfl_xor(p,4); p += __shfl_xor(p,8);
      if (l15 == 0) atomicAdd(plog + gr0 + wr*32 + mi*16 + kh*4 + reg, p);
    }
  }
}

// ---------------------------------------------------------------------------
// Builders (wave-per-row, vectorized, write pads)
__global__ __launch_bounds__(256) void k_build_Aq(const unsigned short* __restrict__ hb,
    const float* __restrict__ tv, const int* __restrict__ q_rows,
    unsigned short* __restrict__ Aq, int nq){
  int w = blockIdx.x*4 + (threadIdx.x>>6), lane = threadIdx.x & 63;
  int nw = gridDim.x*4;
  for (int i = w; i < nq; i += nw){
    int row = q_rows[i]; int b = row & (B_-1);
    unsigned short* dst = Aq + (size_t)i*512;
    if (row < B_){
      for (int j2 = lane; j2 < 225; j2 += 64) ((unsigned int*)dst)[j2] = 0u;
    } else {
      const unsigned int* src = (const unsigned int*)(hb + (size_t)(row-B_)*H_);
      for (int j2 = lane; j2 < 225; j2 += 64) ((unsigned int*)dst)[j2] = src[j2];
    }
    int k = 450 + lane;
    if (k < 512){
      unsigned short v = 0;
      if (k < 506) v = f2b(tv[b*L_ + (k-450)]);
      dst[k] = v;
    }
  }
}

__global__ __launch_bounds__(256) void k_build_Ap(const unsigned short* __restrict__ hb,
    const unsigned short* __restrict__ xb, const float* __restrict__ tv,
    const int* __restrict__ root_ids, const int* __restrict__ step_v,
    unsigned short* __restrict__ Ap){
  int w = blockIdx.x*4 + (threadIdx.x>>6), lane = threadIdx.x & 63;
  int nw = gridDim.x*4;
  for (int i = w; i < NPROWS; i += nw){
    int b = i & (B_-1);
    unsigned short* dst = Ap + (size_t)i*960;
    int xn = (i < B_) ? root_ids[b] : step_v[i - B_];
    const unsigned int* xr = (const unsigned int*)(xb + (size_t)xn*KS);
    for (int j2 = lane; j2 < 225; j2 += 64) ((unsigned int*)dst)[j2] = xr[j2];
    if (i < B_){
      for (int j2 = lane; j2 < 225; j2 += 64) ((unsigned int*)(dst + 450))[j2] = 0u;
    } else {
      const unsigned int* hr = (const unsigned int*)(hb + (size_t)(i-B_)*H_);
      for (int j2 = lane; j2 < 225; j2 += 64) ((unsigned int*)(dst + 450))[j2] = hr[j2];
    }
    int k = 900 + lane;
    if (k < 960){
      unsigned short v = 0;
      if (k < 956) v = f2b(tv[b*L_ + (k-900)]);
      dst[k] = v;
    }
  }
}

// ---------------------------------------------------------------------------
// q reduce: wave-per-row, register-cached row, shuffle reductions
__global__ __launch_bounds__(256) void k_qreduce2(const float* __restrict__ logits,
    const int* __restrict__ q_tgt, int nq, float* __restrict__ out){
  int w = blockIdx.x*4 + (threadIdx.x>>6), lane = threadIdx.x & 63;
  int nw = gridDim.x*4;
  float qloss = 0.f, qacc = 0.f;
  for (int i = w; i < nq; i += nw){
    const float4* lr4 = (const float4*)(logits + (size_t)i*V_);
    float4 vals[4]; int cnt = 0;
    float mx = -INFINITY; int mi = 0x7fffffff;
    for (int j4 = lane; j4 < 195; j4 += 64){
      float4 v = lr4[j4]; vals[cnt++] = v;
      #pragma unroll
      for (int u = 0; u < 4; ++u){
        float f = ((float*)&v)[u];
        if (f > mx){ mx = f; mi = j4*4 + u; }
      }
    }
    #pragma unroll
    for (int off = 32; off; off >>= 1){
      float omx = __shfl_xor(mx, off); int omi = __shfl_xor(mi, off);
      if (omx > mx || (omx == mx && omi < mi)){ mx = omx; mi = omi; }
    }
    float ps = 0.f; cnt = 0;
    for (int j4 = lane; j4 < 195; j4 += 64){
      float4 v = vals[cnt++];
      ps += expf(v.x-mx) + expf(v.y-mx) + expf(v.z-mx) + expf(v.w-mx);
    }
    #pragma unroll
    for (int off = 32; off; off >>= 1) ps += __shfl_xor(ps, off);
    if (lane == 0){
      int tg = q_tgt[i];
      float lt = logits[(size_t)i*V_ + tg];
      qloss += mx + logf(ps) - lt;
      qacc  += (mi == tg) ? 1.f : 0.f;
    }
  }
  if (lane == 0){
    atomicAdd(out+0, qloss*(1.0f/B_));
    atomicAdd(out+2, qacc *(1.0f/(float)nq));
  }
}

// p final: BCE + acc from plog
__global__ __launch_bounds__(256) void k_pfinal(const float* __restrict__ plog,
    const float* __restrict__ bs, const int* __restrict__ p_tgt, float* __restrict__ out){
  int i = blockIdx.x*256 + threadIdx.x;
  float loss = 0.f, acc = 0.f;
  if (i < NPROWS){
    float pl = plog[i] + bs[0];
    float tgt = (float)p_tgt[i];
    loss = fmaxf(pl, 0.f) + log1pf(expf(-fabsf(pl))) - pl*tgt;
    acc = (((pl > 0.f) ? 1 : 0) == p_tgt[i]) ? 1.f : 0.f;
  }
  #pragma unroll
  for (int off = 32; off; off >>= 1){
    loss += __shfl_xor(loss, off); acc += __shfl_xor(acc, off);
  }
  if ((threadIdx.x & 63) == 0){
    atomicAdd(out+1, loss*(1.0f/B_));
    atomicAdd(out+3, acc *(1.0f/(float)NPROWS));
  }
}

// ---------------------------------------------------------------------------
extern "C" void kernel_launch(void* const* d_in, const int* in_sizes, int n_in,
                              void* d_out, int out_size, void* d_ws, size_t ws_size,
                              hipStream_t stream){
  const float* tree_vec = (const float*)d_in[0];
  const float* emb  = (const float*)d_in[1];
  const float* Wz   = (const float*)d_in[2];
  const float* bz   = (const float*)d_in[3];
  const float* Wh   = (const float*)d_in[4];
  const float* bh   = (const float*)d_in[5];
  const float* Wr   = (const float*)d_in[6];
  const float* Ur   = (const float*)d_in[7];
  const float* br   = (const float*)d_in[8];
  const float* Ww   = (const float*)d_in[9];
  const float* bw   = (const float*)d_in[10];
  const float* Uw   = (const float*)d_in[11];
  const float* bu   = (const float*)d_in[12];
  const float* Wo   = (const float*)d_in[13];
  const float* bo   = (const float*)d_in[14];
  const float* Us   = (const float*)d_in[15];
  const float* bs   = (const float*)d_in[16];
  const int* wid      = (const int*)d_in[17];
  const int* root_ids = (const int*)d_in[18];
  const int* edge_src = (const int*)d_in[19];
  const int* edge_dst = (const int*)d_in[20];
  const int* edge_pred= (const int*)d_in[21];
  const int* node_in  = (const int*)d_in[22];
  const int* step_eid = (const int*)d_in[23];
  const int* step_v   = (const int*)d_in[24];
  const int* q_rows   = (const int*)d_in[25];
  const int* q_tgt    = (const int*)d_in[26];
  const int* p_tgt    = (const int*)d_in[27];
  int P  = in_sizes[21] / NEDGES;  if (P > MAXP) P = MAXP;
  int Dn = in_sizes[22] / NNODES;  if (Dn > MAXD) Dn = MAXD;
  int nq = in_sizes[25];           // 10240

  char* ws = (char*)d_ws;
  // --- layout ---
  const size_t XB_OFF  = 0;                         // bf16 [10240][480] = 9,830,400
  const size_t HB_OFF  = 9830400;                   // bf16 [19456][450] = 17,510,400
  const size_t M_OFF   = 27340800;                  // bf16 [19457][480] = 18,678,720 (pad 18,678,784)
  const size_t RM_OFF  = M_OFF + 18678784;          // = 46,019,584
  const size_t WZB_OFF = RM_OFF + 18678784;         // = 64,698,368  bf16 [512][480]
  const size_t WHB_OFF = WZB_OFF + 491520;
  const size_t URT_OFF = WHB_OFF + 491520;
  const size_t WZTOP_OFF = URT_OFF + 491520;        // = 66,172,928
  const size_t WHTOP_OFF = WZTOP_OFF + 491520;
  const size_t WRT_OFF   = WHTOP_OFF + 491520;
  const size_t WWT_OFF = WRT_OFF + 491520;          // = 67,647,488  bf16 [512][512]
  const size_t UWT_OFF = WWT_OFF + 524288;          // bf16 [512][960]
  const size_t WOT_OFF = UWT_OFF + 983040;          // bf16 [832][512]
  const size_t XWZ_OFF = WOT_OFF + 851968;          // = 70,006,784  bf16 [10240][450]
  const size_t XWH_OFF = XWZ_OFF + 9216000;
  const size_t XWR_OFF = XWH_OFF + 9216000;         // ends 97,654,784
  // overlays after scan:
  const size_t LQ_OFF  = M_OFF;                     // f32 [10240][780] = 31,948,800 (fits M+RM)
  const size_t AQ_OFF  = XWZ_OFF;                   // bf16 [10240][512] (XW dead post-scan)
  const size_t HQB_OFF = AQ_OFF + 10485760;
  const size_t PL_OFF  = HQB_OFF + 10485760;        // f32 [19968]
  const size_t AP_OFF  = M_OFF;                     // bf16 [19968][960] = 38,338,560 (covers M..scan-weights, all dead)

  unsigned short* xb = (unsigned short*)(ws + XB_OFF);
  unsigned short* hb = (unsigned short*)(ws + HB_OFF);
  unsigned short* m_ = (unsigned short*)(ws + M_OFF);
  unsigned short* rm = (unsigned short*)(ws + RM_OFF);
  unsigned short* WzB = (unsigned short*)(ws + WZB_OFF);
  unsigned short* WhB = (unsigned short*)(ws + WHB_OFF);
  unsigned short* UrT = (unsigned short*)(ws + URT_OFF);
  unsigned short* WzTop = (unsigned short*)(ws + WZTOP_OFF);
  unsigned short* WhTop = (unsigned short*)(ws + WHTOP_OFF);
  unsigned short* WrT = (unsigned short*)(ws + WRT_OFF);
  unsigned short* WwT = (unsigned short*)(ws + WWT_OFF);
  unsigned short* UwT = (unsigned short*)(ws + UWT_OFF);
  unsigned short* WoT = (unsigned short*)(ws + WOT_OFF);
  unsigned short* XWz = (unsigned short*)(ws + XWZ_OFF);
  unsigned short* XWh = (unsigned short*)(ws + XWH_OFF);
  unsigned short* XWr = (unsigned short*)(ws + XWR_OFF);

  hipMemsetAsync(ws + M_OFF, 0, 2*18678784ull, stream);   // m, rm (incl sentinel+pads)
  hipMemsetAsync(d_out, 0, (size_t)out_size*sizeof(float), stream);

  k_gather_xb<<<2560, 256, 0, stream>>>(emb, wid, xb);

  // scan weights: bottom halves (K rows 450..899) + Ur; top halves for XW precompute
  k_wt<<<512, 256, 0, stream>>>(Wz + 450*450, Wz, 450, 450, 450, WzB, KS);
  k_wt<<<512, 256, 0, stream>>>(Wh + 450*450, Wh, 450, 450, 450, WhB, KS);
  k_wt<<<512, 256, 0, stream>>>(Ur, Ur, 450, 450, 450, UrT, KS);
  k_wt<<<512, 256, 0, stream>>>(Wz, Wz, 450, 450, 450, WzTop, KS);
  k_wt<<<512, 256, 0, stream>>>(Wh, Wh, 450, 450, 450, WhTop, KS);
  k_wt<<<512, 256, 0, stream>>>(Wr, Wr, 450, 450, 450, WrT, KS);
  k_wt<<<512, 256, 0, stream>>>(Ww, Ww, 506, 506, 450, WwT, 512);
  k_wt<<<512, 256, 0, stream>>>(Uw, Uw, 956, 956, 450, UwT, 960);
  k_wt<<<832, 256, 0, stream>>>(Wo, Wo, 450, 450, 780, WoT, 512);

  // XW precompute (bias folded): XWz = xb@WzTop + bz, etc.  [10240][450] bf16
  k_head_mfma<<<dim3(8,160), 256, 0, stream>>>(xb, WzTop, KS, bz, H_, 0, nullptr, 0, XWz, H_);
  k_head_mfma<<<dim3(8,160), 256, 0, stream>>>(xb, WhTop, KS, bh, H_, 0, nullptr, 0, XWh, H_);
  k_head_mfma<<<dim3(8,160), 256, 0, stream>>>(xb, WrT,   KS, br, H_, 0, nullptr, 0, XWr, H_);

  // ---- cooperative fused scan ----
  ScanP sp;
  sp.WzB = WzB; sp.WhB = WhB; sp.UrT = UrT;
  sp.XWz = XWz; sp.XWh = XWh; sp.XWr = XWr;
  sp.edge_src = edge_src; sp.edge_dst = edge_dst; sp.edge_pred = edge_pred;
  sp.node_in = node_in; sp.step_eid = step_eid; sp.step_v = step_v;
  sp.m = m_; sp.rm = rm; sp.hb = hb;
  sp.P = P; sp.Dn = Dn;
  void* kargs[] = { &sp };
  hipLaunchCooperativeKernel(k_scan_coop, dim3(64), dim3(1024), kargs, 0, stream);

  // ---- q head ----
  unsigned short* Aq  = (unsigned short*)(ws + AQ_OFF);
  float* logitsq      = (float*)(ws + LQ_OFF);
  unsigned short* hqb = (unsigned short*)(ws + HQB_OFF);
  float* plog         = (float*)(ws + PL_OFF);
  hipMemsetAsync(plog, 0, (size_t)NPROWS*4, stream);

  k_build_Aq<<<640, 256, 0, stream>>>(hb, tree_vec, q_rows, Aq, nq);
  k_head_mfma<<<dim3(8, nq/64), 256, 0, stream>>>(Aq, WwT, 512, bw, H_, 1,
      nullptr, 0, hqb, 512);
  k_head_mfma<<<dim3(13, nq/64), 256, 0, stream>>>(hqb, WoT, 512, bo, V_, 0,
      logitsq, V_, nullptr, 0);
  k_qreduce2<<<320, 256, 0, stream>>>(logitsq, q_tgt, nq, (float*)d_out);

  // ---- p head ----
  unsigned short* Ap = (unsigned short*)(ws + AP_OFF);
  k_build_Ap<<<1248, 256, 0, stream>>>(hb, xb, tree_vec, root_ids, step_v, Ap);
  k_head_p<<<dim3(8, NPROWS/64), 256, 0, stream>>>(Ap, UwT, bu, Us, plog);
  k_pfinal<<<78, 256, 0, stream>>>(plog, bs, p_tgt, (float*)d_out);
}

// Round 8
// 1726.975 us; speedup vs baseline: 2.3721x; 2.3721x over previous
//
#include <hip/hip_runtime.h>
#include <math.h>

#define B_ 512
#define N_ 20
#define H_ 450
#define L_ 56
#define V_ 780
#define T_ 38
#define NNODES (B_*N_)        // 10240
#define NEDGES (B_*2*(N_-1))  // 19456
#define NPROWS ((T_+1)*B_)    // 19968
#define MAXP 8
#define MAXD 8
#define KS 480                // scan K pad (450 -> 480 = 15*32); also m/rm row stride
#define AST 488               // A-tile LDS row stride in shorts (976B, 16B-aligned)

typedef __attribute__((ext_vector_type(8))) short bf16x8;
typedef __attribute__((ext_vector_type(4))) float f32x4;

__device__ __forceinline__ float sigmoidf_(float v){ return 1.0f/(1.0f+expf(-v)); }

__device__ __forceinline__ unsigned short f2b(float x){
  unsigned int u = __float_as_uint(x);
  unsigned int r = (u + 0x7fffu + ((u >> 16) & 1u)) >> 16;
  return (unsigned short)r;
}
__device__ __forceinline__ float b2f(unsigned short v){
  return __uint_as_float((unsigned int)v << 16);
}
__device__ __forceinline__ unsigned int pack2(float lo, float hi){
  return (unsigned int)f2b(lo) | ((unsigned int)f2b(hi) << 16);
}

// ---------------------------------------------------------------------------
// xb[i][:] = bf16(emb[wid[i]][:]), K-padded to 480
__global__ __launch_bounds__(256) void k_gather_xb(const float* __restrict__ emb,
    const int* __restrict__ wid, unsigned short* __restrict__ xb){
  int w = blockIdx.x*4 + (threadIdx.x>>6), lane = threadIdx.x & 63;
  if (w >= NNODES) return;
  const float2* src = (const float2*)(emb + (size_t)wid[w]*H_);
  unsigned int* dst = (unsigned int*)(xb + (size_t)w*KS);
  for (int j2 = lane; j2 < 240; j2 += 64){
    unsigned int v = 0;
    if (j2 < 225){ float2 f = src[j2]; v = pack2(f.x, f.y); }
    dst[j2] = v;
  }
}

// Transpose+convert weight to K-major bf16 with zero padding.
__global__ void k_wt(const float* __restrict__ W1, const float* __restrict__ W2,
                     int Ksplit, int Kact, int Nact, unsigned short* __restrict__ dst, int Kpad){
  int c = blockIdx.x;
  unsigned short* drow = dst + (size_t)c*Kpad;
  for (int k = threadIdx.x; k < Kpad; k += blockDim.x){
    float v = 0.f;
    if (c < Nact && k < Kact)
      v = (k < Ksplit) ? W1[(size_t)k*Nact + c] : W2[(size_t)(k-Ksplit)*Nact + c];
    drow[k] = f2b(v);
  }
}

// ---------------------------------------------------------------------------
struct ScanP {
  const unsigned short *WzB, *WhB, *UrT;        // [512][480] K-major bf16
  const unsigned short *XWz, *XWh, *XWr;        // [10240][450] bf16, bias folded in
  const int *edge_src, *edge_dst, *edge_pred, *node_in, *step_eid, *step_v;
  unsigned short *m, *rm, *hb;                  // m/rm [NEDGES+1][480], hb [T*B][450]
  int P, Dn;
};

// Tree-owned scan: 32 blocks x 16 trees, NO cross-block deps, NO grid syncs.
// 1024 thr = 16 waves; wave wv owns output cols [32wv,32wv+32). L2 stays warm.
__global__ __launch_bounds__(1024) void k_scan_tree(ScanP p){
  __shared__ unsigned short A1s[16*AST];   // [s] bf16 (K-padded, rows = trees)
  __shared__ unsigned short A2s[16*AST];   // [arm] -> m_new after gate epilogue
  __shared__ float SL[16*KS];              // f32 pred-sum s
  __shared__ int s_moff[16], s_src[16], s_dst[16], s_pcnt[16], s_dcnt[16];
  __shared__ int s_poff[16][MAXP];
  __shared__ int s_noff[16][MAXD];

  const int tid = threadIdx.x;
  const int lane = tid & 63, l15 = lane & 15, kh = lane >> 4, ko = kh*8;
  const int wv = tid >> 6;
  const int r0 = blockIdx.x * 16;
  const int P = p.P, Dn = p.Dn;
  const int gr = tid >> 6, gsub = tid & 63;     // gather: 64 threads per tree
  const int c_0 = wv*32 + l15, c_1 = c_0 + 16;  // this lane's two output cols

  const unsigned short* pWz0 = p.WzB + (size_t)c_0*KS;
  const unsigned short* pWz1 = p.WzB + (size_t)c_1*KS;
  const unsigned short* pWh0 = p.WhB + (size_t)c_0*KS;
  const unsigned short* pWh1 = p.WhB + (size_t)c_1*KS;
  const unsigned short* pUr0 = p.UrT + (size_t)c_0*KS;
  const unsigned short* pUr1 = p.UrT + (size_t)c_1*KS;
  const unsigned short* aA1 = A1s + l15*AST;    // A row = tree = l15
  const unsigned short* aA2 = A2s + l15*AST;

  for (int t = 0; t < T_; ++t){
    if (tid < 16){
      int b = r0 + tid;
      int e = p.step_eid[t*B_ + b];
      s_moff[tid] = e*KS;
      s_src[tid] = p.edge_src[e]*H_;
      s_dst[tid] = p.edge_dst[e]*H_;
      int pc = 0;
      for (int q = 0; q < P; ++q){
        int pe = p.edge_pred[e*P + q];
        if (pe != NEDGES) s_poff[tid][pc++] = pe*KS;
      }
      s_pcnt[tid] = pc;
      int v = p.step_v[t*B_ + b];
      int dc = 0;
      for (int d = 0; d < Dn; ++d){
        int ne = p.node_in[v*Dn + d];
        if (ne != NEDGES) s_noff[tid][dc++] = ne*KS;
      }
      s_dcnt[tid] = dc;
    }
    __syncthreads();   // (1) meta ready; prev-step reads of A1s/A2s done

    // ---- gather: A1=[s] bf16, A2=[arm] bf16, SL=s f32 ----
    {
      int pc = s_pcnt[gr];
      uint2* d1 = (uint2*)(A1s + gr*AST);
      uint2* d2 = (uint2*)(A2s + gr*AST);
      float* sl = SL + gr*KS;
      for (int j4 = gsub; j4 < 120; j4 += 64){
        float f0=0.f,f1=0.f,f2=0.f,f3=0.f;
        float g0=0.f,g1=0.f,g2=0.f,g3=0.f;
        for (int q = 0; q < pc; ++q){
          int o = s_poff[gr][q] + 4*j4;
          uint2 mv = *(const uint2*)(p.m + o);
          uint2 rv = *(const uint2*)(p.rm + o);
          f0 += b2f((unsigned short)(mv.x & 0xffff)); f1 += b2f((unsigned short)(mv.x >> 16));
          f2 += b2f((unsigned short)(mv.y & 0xffff)); f3 += b2f((unsigned short)(mv.y >> 16));
          g0 += b2f((unsigned short)(rv.x & 0xffff)); g1 += b2f((unsigned short)(rv.x >> 16));
          g2 += b2f((unsigned short)(rv.y & 0xffff)); g3 += b2f((unsigned short)(rv.y >> 16));
        }
        uint2 w1; w1.x = pack2(f0,f1); w1.y = pack2(f2,f3);
        uint2 w2; w2.x = pack2(g0,g1); w2.y = pack2(g2,g3);
        d1[j4] = w1; d2[j4] = w2;
        sl[4*j4] = f0; sl[4*j4+1] = f1; sl[4*j4+2] = f2; sl[4*j4+3] = f3;
      }
    }
    __syncthreads();   // (2) A tiles + SL ready

    // ---- gate K-loop (barrier-free; B from warm L2) ----
    f32x4 accZ0 = {}, accZ1 = {}, accH0 = {}, accH1 = {};
    #pragma unroll
    for (int it = 0; it < 15; ++it){
      bf16x8 a1  = *(const bf16x8*)(aA1 + it*32 + ko);
      bf16x8 a2  = *(const bf16x8*)(aA2 + it*32 + ko);
      bf16x8 bz0 = *(const bf16x8*)(pWz0 + it*32 + ko);
      bf16x8 bz1 = *(const bf16x8*)(pWz1 + it*32 + ko);
      bf16x8 bh0 = *(const bf16x8*)(pWh0 + it*32 + ko);
      bf16x8 bh1 = *(const bf16x8*)(pWh1 + it*32 + ko);
      accZ0 = __builtin_amdgcn_mfma_f32_16x16x32_bf16(a1,bz0,accZ0,0,0,0);
      accZ1 = __builtin_amdgcn_mfma_f32_16x16x32_bf16(a1,bz1,accZ1,0,0,0);
      accH0 = __builtin_amdgcn_mfma_f32_16x16x32_bf16(a2,bh0,accH0,0,0,0);
      accH1 = __builtin_amdgcn_mfma_f32_16x16x32_bf16(a2,bh1,accH1,0,0,0);
    }
    __syncthreads();   // (3) all waves done reading A2s (arm)

    // ---- gate epilogue: m_new -> global m + LDS (A2s) ----
    #pragma unroll
    for (int n = 0; n < 2; ++n){
      int cc = wv*32 + n*16 + l15;
      if (cc < H_){
        f32x4 aZ = n ? accZ1 : accZ0;
        f32x4 aH = n ? accH1 : accH0;
        #pragma unroll
        for (int reg = 0; reg < 4; ++reg){
          int rl = kh*4 + reg;
          float z  = sigmoidf_(aZ[reg] + b2f(p.XWz[s_src[rl] + cc]));
          float th = tanhf   (aH[reg] + b2f(p.XWh[s_src[rl] + cc]));
          float s_ = SL[rl*KS + cc];
          float mn = (1.f - z)*s_ + z*th;
          unsigned short mb = f2b(mn);
          p.m[s_moff[rl] + cc] = mb;
          A2s[rl*AST + cc] = mb;
        }
      }
    }
    __syncthreads();   // (4) m_new in A2s complete

    // ---- rgate K-loop: R = m_new@Ur (A from LDS, B from warm L2) ----
    f32x4 accR0 = {}, accR1 = {};
    #pragma unroll
    for (int it = 0; it < 15; ++it){
      bf16x8 a  = *(const bf16x8*)(aA2 + it*32 + ko);
      bf16x8 b0 = *(const bf16x8*)(pUr0 + it*32 + ko);
      bf16x8 b1 = *(const bf16x8*)(pUr1 + it*32 + ko);
      accR0 = __builtin_amdgcn_mfma_f32_16x16x32_bf16(a,b0,accR0,0,0,0);
      accR1 = __builtin_amdgcn_mfma_f32_16x16x32_bf16(a,b1,accR1,0,0,0);
    }

    // ---- rgate epilogue: rm, h-pull ----
    #pragma unroll
    for (int n = 0; n < 2; ++n){
      int cc = wv*32 + n*16 + l15;
      if (cc < H_){
        f32x4 aR = n ? accR1 : accR0;
        #pragma unroll
        for (int reg = 0; reg < 4; ++reg){
          int rl = kh*4 + reg;
          float r_ = sigmoidf_(aR[reg] + b2f(p.XWr[s_dst[rl] + cc]));
          float mn = b2f(A2s[rl*AST + cc]);
          p.rm[s_moff[rl] + cc] = f2b(r_*mn);
          float h = 0.f;
          int dc = s_dcnt[rl];
          for (int d = 0; d < dc; ++d) h += b2f(p.m[s_noff[rl][d] + cc]);
          p.hb[(size_t)(t*B_ + r0 + rl)*H_ + cc] = f2b(h);
        }
      }
    }
    // loop-top barrier (1) protects meta/A1s/A2s for next step
  }
}

// ---------------------------------------------------------------------------
// MFMA tile core for heads: 64x64 tile, 4 waves (2x2), BK=32, K-major bf16.
__device__ __forceinline__ void mfma_tile_core(
    const unsigned short* __restrict__ A, const unsigned short* __restrict__ BT,
    int K, int gr0, int gc0, int tid,
    unsigned short* __restrict__ As, unsigned short* __restrict__ Bs,
    f32x4 (&acc)[2][2])
{
  const int lane = tid & 63;
  const int w = tid >> 6, wr = w >> 1, wc = w & 1;
  const int l15 = lane & 15, kh = lane >> 4;
  const int sr = tid >> 2, sj = (tid & 3) * 8;
  const size_t arow = (size_t)(gr0 + sr) * K;
  const size_t brow = (size_t)(gc0 + sr) * K;
  for (int kt = 0; kt < K; kt += 32){
    __syncthreads();
    *(float4*)&As[sr*40 + sj] = *(const float4*)&A[arow + kt + sj];
    *(float4*)&Bs[sr*40 + sj] = *(const float4*)&BT[brow + kt + sj];
    __syncthreads();
    bf16x8 a0 = *(const bf16x8*)&As[(wr*32      + l15)*40 + kh*8];
    bf16x8 a1 = *(const bf16x8*)&As[(wr*32 + 16 + l15)*40 + kh*8];
    bf16x8 b0 = *(const bf16x8*)&Bs[(wc*32      + l15)*40 + kh*8];
    bf16x8 b1 = *(const bf16x8*)&Bs[(wc*32 + 16 + l15)*40 + kh*8];
    acc[0][0] = __builtin_amdgcn_mfma_f32_16x16x32_bf16(a0,b0,acc[0][0],0,0,0);
    acc[0][1] = __builtin_amdgcn_mfma_f32_16x16x32_bf16(a0,b1,acc[0][1],0,0,0);
    acc[1][0] = __builtin_amdgcn_mfma_f32_16x16x32_bf16(a1,b0,acc[1][0],0,0,0);
    acc[1][1] = __builtin_amdgcn_mfma_f32_16x16x32_bf16(a1,b1,acc[1][1],0,0,0);
  }
}

// Head GEMM: C = act(A@B + bias); f32 store and/or bf16 store.
__global__ __launch_bounds__(256) void k_head_mfma(
    const unsigned short* __restrict__ A, const unsigned short* __restrict__ BT, int K,
    const float* __restrict__ bias, int Nact, int relu,
    float* __restrict__ outF, int ldF, unsigned short* __restrict__ outB, int ldB)
{
  __shared__ unsigned short As[64*40], Bs[64*40];
  const int tid = threadIdx.x;
  const int gr0 = blockIdx.y*64, gc0 = blockIdx.x*64;
  f32x4 acc[2][2] = {};
  mfma_tile_core(A, BT, K, gr0, gc0, tid, As, Bs, acc);
  const int lane = tid & 63;
  const int w = tid >> 6, wr = w >> 1, wc = w & 1;
  const int l15 = lane & 15, kh = lane >> 4;
  #pragma unroll
  for (int mi = 0; mi < 2; ++mi){
    #pragma unroll
    for (int n = 0; n < 2; ++n){
      int c = gc0 + wc*32 + n*16 + l15;
      float bc = (c < Nact) ? bias[c] : 0.f;
      #pragma unroll
      for (int reg = 0; reg < 4; ++reg){
        int r = gr0 + wr*32 + mi*16 + kh*4 + reg;
        float v = acc[mi][n][reg] + bc;
        if (relu) v = fmaxf(v, 0.f);
        if (outF && c < Nact) outF[(size_t)r*ldF + c] = v;
        if (outB && c < ldB)  outB[(size_t)r*ldB + c] = (c < Nact) ? f2b(v) : (unsigned short)0;
      }
    }
  }
}

// p-head GEMM with fused Us-dot: plog[r] += sum_c relu(acc+bu)*Us[c]
__global__ __launch_bounds__(256) void k_head_p(
    const unsigned short* __restrict__ A, const unsigned short* __restrict__ BT,
    const float* __restrict__ bu_, const float* __restrict__ Us, float* __restrict__ plog)
{
  __shared__ unsigned short As[64*40], Bs[64*40];
  const int tid = threadIdx.x;
  const int gr0 = blockIdx.y*64, gc0 = blockIdx.x*64;
  f32x4 acc[2][2] = {};
  mfma_tile_core(A, BT, 960, gr0, gc0, tid, As, Bs, acc);
  const int lane = tid & 63;
  const int w = tid >> 6, wr = w >> 1, wc = w & 1;
  const int l15 = lane & 15, kh = lane >> 4;
  #pragma unroll
  for (int mi = 0; mi < 2; ++mi){
    float rowsum[4] = {0.f,0.f,0.f,0.f};
    #pragma unroll
    for (int n = 0; n < 2; ++n){
      int c = gc0 + wc*32 + n*16 + l15;
      float uc = 0.f, bc = 0.f;
      if (c < H_){ uc = Us[c]; bc = bu_[c]; }
      #pragma unroll
      for (int reg = 0; reg < 4; ++reg){
        float v = fmaxf(acc[mi][n][reg] + bc, 0.f);
        rowsum[reg] += (c < H_) ? v*uc : 0.f;
      }
    }
    #pragma unroll
    for (int reg = 0; reg < 4; ++reg){
      float p = rowsum[reg];
      p += __shfl_xor(p,1); p += __shfl_xor(p,2);
      p += __shfl_xor(p,4); p += __shfl_xor(p,8);
      if (l15 == 0) atomicAdd(plog + gr0 + wr*32 + mi*16 + kh*4 + reg, p);
    }
  }
}

// ---------------------------------------------------------------------------
// Builders (wave-per-row, vectorized, write pads)
__global__ __launch_bounds__(256) void k_build_Aq(const unsigned short* __restrict__ hb,
    const float* __restrict__ tv, const int* __restrict__ q_rows,
    unsigned short* __restrict__ Aq, int nq){
  int w = blockIdx.x*4 + (threadIdx.x>>6), lane = threadIdx.x & 63;
  int nw = gridDim.x*4;
  for (int i = w; i < nq; i += nw){
    int row = q_rows[i]; int b = row & (B_-1);
    unsigned short* dst = Aq + (size_t)i*512;
    if (row < B_){
      for (int j2 = lane; j2 < 225; j2 += 64) ((unsigned int*)dst)[j2] = 0u;
    } else {
      const unsigned int* src = (const unsigned int*)(hb + (size_t)(row-B_)*H_);
      for (int j2 = lane; j2 < 225; j2 += 64) ((unsigned int*)dst)[j2] = src[j2];
    }
    int k = 450 + lane;
    if (k < 512){
      unsigned short v = 0;
      if (k < 506) v = f2b(tv[b*L_ + (k-450)]);
      dst[k] = v;
    }
  }
}

__global__ __launch_bounds__(256) void k_build_Ap(const unsigned short* __restrict__ hb,
    const unsigned short* __restrict__ xb, const float* __restrict__ tv,
    const int* __restrict__ root_ids, const int* __restrict__ step_v,
    unsigned short* __restrict__ Ap){
  int w = blockIdx.x*4 + (threadIdx.x>>6), lane = threadIdx.x & 63;
  int nw = gridDim.x*4;
  for (int i = w; i < NPROWS; i += nw){
    int b = i & (B_-1);
    unsigned short* dst = Ap + (size_t)i*960;
    int xn = (i < B_) ? root_ids[b] : step_v[i - B_];
    const unsigned int* xr = (const unsigned int*)(xb + (size_t)xn*KS);
    for (int j2 = lane; j2 < 225; j2 += 64) ((unsigned int*)dst)[j2] = xr[j2];
    if (i < B_){
      for (int j2 = lane; j2 < 225; j2 += 64) ((unsigned int*)(dst + 450))[j2] = 0u;
    } else {
      const unsigned int* hr = (const unsigned int*)(hb + (size_t)(i-B_)*H_);
      for (int j2 = lane; j2 < 225; j2 += 64) ((unsigned int*)(dst + 450))[j2] = hr[j2];
    }
    int k = 900 + lane;
    if (k < 960){
      unsigned short v = 0;
      if (k < 956) v = f2b(tv[b*L_ + (k-900)]);
      dst[k] = v;
    }
  }
}

// ---------------------------------------------------------------------------
// q reduce: wave-per-row, register-cached row, shuffle reductions
__global__ __launch_bounds__(256) void k_qreduce2(const float* __restrict__ logits,
    const int* __restrict__ q_tgt, int nq, float* __restrict__ out){
  int w = blockIdx.x*4 + (threadIdx.x>>6), lane = threadIdx.x & 63;
  int nw = gridDim.x*4;
  float qloss = 0.f, qacc = 0.f;
  for (int i = w; i < nq; i += nw){
    const float4* lr4 = (const float4*)(logits + (size_t)i*V_);
    float4 vals[4]; int cnt = 0;
    float mx = -INFINITY; int mi = 0x7fffffff;
    for (int j4 = lane; j4 < 195; j4 += 64){
      float4 v = lr4[j4]; vals[cnt++] = v;
      #pragma unroll
      for (int u = 0; u < 4; ++u){
        float f = ((float*)&v)[u];
        if (f > mx){ mx = f; mi = j4*4 + u; }
      }
    }
    #pragma unroll
    for (int off = 32; off; off >>= 1){
      float omx = __shfl_xor(mx, off); int omi = __shfl_xor(mi, off);
      if (omx > mx || (omx == mx && omi < mi)){ mx = omx; mi = omi; }
    }
    float ps = 0.f; cnt = 0;
    for (int j4 = lane; j4 < 195; j4 += 64){
      float4 v = vals[cnt++];
      ps += expf(v.x-mx) + expf(v.y-mx) + expf(v.z-mx) + expf(v.w-mx);
    }
    #pragma unroll
    for (int off = 32; off; off >>= 1) ps += __shfl_xor(ps, off);
    if (lane == 0){
      int tg = q_tgt[i];
      float lt = logits[(size_t)i*V_ + tg];
      qloss += mx + logf(ps) - lt;
      qacc  += (mi == tg) ? 1.f : 0.f;
    }
  }
  if (lane == 0){
    atomicAdd(out+0, qloss*(1.0f/B_));
    atomicAdd(out+2, qacc *(1.0f/(float)nq));
  }
}

// p final: BCE + acc from plog
__global__ __launch_bounds__(256) void k_pfinal(const float* __restrict__ plog,
    const float* __restrict__ bs, const int* __restrict__ p_tgt, float* __restrict__ out){
  int i = blockIdx.x*256 + threadIdx.x;
  float loss = 0.f, acc = 0.f;
  if (i < NPROWS){
    float pl = plog[i] + bs[0];
    float tgt = (float)p_tgt[i];
    loss = fmaxf(pl, 0.f) + log1pf(expf(-fabsf(pl))) - pl*tgt;
    acc = (((pl > 0.f) ? 1 : 0) == p_tgt[i]) ? 1.f : 0.f;
  }
  #pragma unroll
  for (int off = 32; off; off >>= 1){
    loss += __shfl_xor(loss, off); acc += __shfl_xor(acc, off);
  }
  if ((threadIdx.x & 63) == 0){
    atomicAdd(out+1, loss*(1.0f/B_));
    atomicAdd(out+3, acc *(1.0f/(float)NPROWS));
  }
}

// ---------------------------------------------------------------------------
extern "C" void kernel_launch(void* const* d_in, const int* in_sizes, int n_in,
                              void* d_out, int out_size, void* d_ws, size_t ws_size,
                              hipStream_t stream){
  const float* tree_vec = (const float*)d_in[0];
  const float* emb  = (const float*)d_in[1];
  const float* Wz   = (const float*)d_in[2];
  const float* bz   = (const float*)d_in[3];
  const float* Wh   = (const float*)d_in[4];
  const float* bh   = (const float*)d_in[5];
  const float* Wr   = (const float*)d_in[6];
  const float* Ur   = (const float*)d_in[7];
  const float* br   = (const float*)d_in[8];
  const float* Ww   = (const float*)d_in[9];
  const float* bw   = (const float*)d_in[10];
  const float* Uw   = (const float*)d_in[11];
  const float* bu   = (const float*)d_in[12];
  const float* Wo   = (const float*)d_in[13];
  const float* bo   = (const float*)d_in[14];
  const float* Us   = (const float*)d_in[15];
  const float* bs   = (const float*)d_in[16];
  const int* wid      = (const int*)d_in[17];
  const int* root_ids = (const int*)d_in[18];
  const int* edge_src = (const int*)d_in[19];
  const int* edge_dst = (const int*)d_in[20];
  const int* edge_pred= (const int*)d_in[21];
  const int* node_in  = (const int*)d_in[22];
  const int* step_eid = (const int*)d_in[23];
  const int* step_v   = (const int*)d_in[24];
  const int* q_rows   = (const int*)d_in[25];
  const int* q_tgt    = (const int*)d_in[26];
  const int* p_tgt    = (const int*)d_in[27];
  int P  = in_sizes[21] / NEDGES;  if (P > MAXP) P = MAXP;
  int Dn = in_sizes[22] / NNODES;  if (Dn > MAXD) Dn = MAXD;
  int nq = in_sizes[25];           // 10240

  char* ws = (char*)d_ws;
  // --- layout ---
  const size_t XB_OFF  = 0;                         // bf16 [10240][480] = 9,830,400
  const size_t HB_OFF  = 9830400;                   // bf16 [19456][450] = 17,510,400
  const size_t M_OFF   = 27340800;                  // bf16 [19457][480] (pad 18,678,784)
  const size_t RM_OFF  = M_OFF + 18678784;          // = 46,019,584
  const size_t WZB_OFF = RM_OFF + 18678784;         // = 64,698,368  bf16 [512][480]
  const size_t WHB_OFF = WZB_OFF + 491520;
  const size_t URT_OFF = WHB_OFF + 491520;
  const size_t WZTOP_OFF = URT_OFF + 491520;        // = 66,172,928
  const size_t WHTOP_OFF = WZTOP_OFF + 491520;
  const size_t WRT_OFF   = WHTOP_OFF + 491520;
  const size_t WWT_OFF = WRT_OFF + 491520;          // = 67,647,488  bf16 [512][512]
  const size_t UWT_OFF = WWT_OFF + 524288;          // bf16 [512][960]
  const size_t WOT_OFF = UWT_OFF + 983040;          // bf16 [832][512]
  const size_t XWZ_OFF = WOT_OFF + 851968;          // = 70,006,784  bf16 [10240][450]
  const size_t XWH_OFF = XWZ_OFF + 9216000;
  const size_t XWR_OFF = XWH_OFF + 9216000;         // ends 97,654,784
  // overlays after scan:
  const size_t LQ_OFF  = M_OFF;                     // f32 [10240][780] (fits M+RM)
  const size_t AQ_OFF  = XWZ_OFF;                   // bf16 [10240][512] (XW dead post-scan)
  const size_t HQB_OFF = AQ_OFF + 10485760;
  const size_t PL_OFF  = HQB_OFF + 10485760;        // f32 [19968]
  const size_t AP_OFF  = M_OFF;                     // bf16 [19968][960] (M..weights dead)

  unsigned short* xb = (unsigned short*)(ws + XB_OFF);
  unsigned short* hb = (unsigned short*)(ws + HB_OFF);
  unsigned short* m_ = (unsigned short*)(ws + M_OFF);
  unsigned short* rm = (unsigned short*)(ws + RM_OFF);
  unsigned short* WzB = (unsigned short*)(ws + WZB_OFF);
  unsigned short* WhB = (unsigned short*)(ws + WHB_OFF);
  unsigned short* UrT = (unsigned short*)(ws + URT_OFF);
  unsigned short* WzTop = (unsigned short*)(ws + WZTOP_OFF);
  unsigned short* WhTop = (unsigned short*)(ws + WHTOP_OFF);
  unsigned short* WrT = (unsigned short*)(ws + WRT_OFF);
  unsigned short* WwT = (unsigned short*)(ws + WWT_OFF);
  unsigned short* UwT = (unsigned short*)(ws + UWT_OFF);
  unsigned short* WoT = (unsigned short*)(ws + WOT_OFF);
  unsigned short* XWz = (unsigned short*)(ws + XWZ_OFF);
  unsigned short* XWh = (unsigned short*)(ws + XWH_OFF);
  unsigned short* XWr = (unsigned short*)(ws + XWR_OFF);

  hipMemsetAsync(ws + M_OFF, 0, 2*18678784ull, stream);   // m, rm (incl sentinel+pads)
  hipMemsetAsync(d_out, 0, (size_t)out_size*sizeof(float), stream);

  k_gather_xb<<<2560, 256, 0, stream>>>(emb, wid, xb);

  // scan weights: bottom halves (K rows 450..899) + Ur; top halves for XW precompute
  k_wt<<<512, 256, 0, stream>>>(Wz + 450*450, Wz, 450, 450, 450, WzB, KS);
  k_wt<<<512, 256, 0, stream>>>(Wh + 450*450, Wh, 450, 450, 450, WhB, KS);
  k_wt<<<512, 256, 0, stream>>>(Ur, Ur, 450, 450, 450, UrT, KS);
  k_wt<<<512, 256, 0, stream>>>(Wz, Wz, 450, 450, 450, WzTop, KS);
  k_wt<<<512, 256, 0, stream>>>(Wh, Wh, 450, 450, 450, WhTop, KS);
  k_wt<<<512, 256, 0, stream>>>(Wr, Wr, 450, 450, 450, WrT, KS);
  k_wt<<<512, 256, 0, stream>>>(Ww, Ww, 506, 506, 450, WwT, 512);
  k_wt<<<512, 256, 0, stream>>>(Uw, Uw, 956, 956, 450, UwT, 960);
  k_wt<<<832, 256, 0, stream>>>(Wo, Wo, 450, 450, 780, WoT, 512);

  // XW precompute (bias folded): XWz = xb@WzTop + bz, etc.  [10240][450] bf16
  k_head_mfma<<<dim3(8,160), 256, 0, stream>>>(xb, WzTop, KS, bz, H_, 0, nullptr, 0, XWz, H_);
  k_head_mfma<<<dim3(8,160), 256, 0, stream>>>(xb, WhTop, KS, bh, H_, 0, nullptr, 0, XWh, H_);
  k_head_mfma<<<dim3(8,160), 256, 0, stream>>>(xb, WrT,   KS, br, H_, 0, nullptr, 0, XWr, H_);

  // ---- tree-owned fused scan: no cross-block deps, no grid sync ----
  ScanP sp;
  sp.WzB = WzB; sp.WhB = WhB; sp.UrT = UrT;
  sp.XWz = XWz; sp.XWh = XWh; sp.XWr = XWr;
  sp.edge_src = edge_src; sp.edge_dst = edge_dst; sp.edge_pred = edge_pred;
  sp.node_in = node_in; sp.step_eid = step_eid; sp.step_v = step_v;
  sp.m = m_; sp.rm = rm; sp.hb = hb;
  sp.P = P; sp.Dn = Dn;
  k_scan_tree<<<32, 1024, 0, stream>>>(sp);

  // ---- q head ----
  unsigned short* Aq  = (unsigned short*)(ws + AQ_OFF);
  float* logitsq      = (float*)(ws + LQ_OFF);
  unsigned short* hqb = (unsigned short*)(ws + HQB_OFF);
  float* plog         = (float*)(ws + PL_OFF);
  hipMemsetAsync(plog, 0, (size_t)NPROWS*4, stream);

  k_build_Aq<<<640, 256, 0, stream>>>(hb, tree_vec, q_rows, Aq, nq);
  k_head_mfma<<<dim3(8, nq/64), 256, 0, stream>>>(Aq, WwT, 512, bw, H_, 1,
      nullptr, 0, hqb, 512);
  k_head_mfma<<<dim3(13, nq/64), 256, 0, stream>>>(hqb, WoT, 512, bo, V_, 0,
      logitsq, V_, nullptr, 0);
  k_qreduce2<<<320, 256, 0, stream>>>(logitsq, q_tgt, nq, (float*)d_out);

  // ---- p head ----
  unsigned short* Ap = (unsigned short*)(ws + AP_OFF);
  k_build_Ap<<<1248, 256, 0, stream>>>(hb, xb, tree_vec, root_ids, step_v, Ap);
  k_head_p<<<dim3(8, NPROWS/64), 256, 0, stream>>>(Ap, UwT, bu, Us, plog);
  k_pfinal<<<78, 256, 0, stream>>>(plog, bs, p_tgt, (float*)d_out);
}

// Round 9
// 1647.532 us; speedup vs baseline: 2.4865x; 1.0482x over previous
//
#include <hip/hip_runtime.h>
#include <math.h>

#define B_ 512
#define N_ 20
#define H_ 450
#define L_ 56
#define V_ 780
#define T_ 38
#define NNODES (B_*N_)        // 10240
#define NEDGES (B_*2*(N_-1))  // 19456
#define NPROWS ((T_+1)*B_)    // 19968
#define MAXP 8
#define MAXD 8
#define KS 480                // scan K pad (450 -> 480 = 15*32); also m/rm row stride
#define AST 488               // A-tile LDS row stride in shorts (976B, 16B-aligned)
#define NT 8                  // trees per block
#define XST 456               // XW-stage LDS row stride in shorts (912B)

typedef __attribute__((ext_vector_type(8))) short bf16x8;
typedef __attribute__((ext_vector_type(4))) float f32x4;

__device__ __forceinline__ float sigmoidf_(float v){ return 1.0f/(1.0f+expf(-v)); }

__device__ __forceinline__ unsigned short f2b(float x){
  unsigned int u = __float_as_uint(x);
  unsigned int r = (u + 0x7fffu + ((u >> 16) & 1u)) >> 16;
  return (unsigned short)r;
}
__device__ __forceinline__ float b2f(unsigned short v){
  return __uint_as_float((unsigned int)v << 16);
}
__device__ __forceinline__ unsigned int pack2(float lo, float hi){
  return (unsigned int)f2b(lo) | ((unsigned int)f2b(hi) << 16);
}

// ---------------------------------------------------------------------------
// xb[i][:] = bf16(emb[wid[i]][:]), K-padded to 480
__global__ __launch_bounds__(256) void k_gather_xb(const float* __restrict__ emb,
    const int* __restrict__ wid, unsigned short* __restrict__ xb){
  int w = blockIdx.x*4 + (threadIdx.x>>6), lane = threadIdx.x & 63;
  if (w >= NNODES) return;
  const float2* src = (const float2*)(emb + (size_t)wid[w]*H_);
  unsigned int* dst = (unsigned int*)(xb + (size_t)w*KS);
  for (int j2 = lane; j2 < 240; j2 += 64){
    unsigned int v = 0;
    if (j2 < 225){ float2 f = src[j2]; v = pack2(f.x, f.y); }
    dst[j2] = v;
  }
}

// Transpose+convert weight to K-major bf16 with zero padding.
__global__ void k_wt(const float* __restrict__ W1, const float* __restrict__ W2,
                     int Ksplit, int Kact, int Nact, unsigned short* __restrict__ dst, int Kpad){
  int c = blockIdx.x;
  unsigned short* drow = dst + (size_t)c*Kpad;
  for (int k = threadIdx.x; k < Kpad; k += blockDim.x){
    float v = 0.f;
    if (c < Nact && k < Kact)
      v = (k < Ksplit) ? W1[(size_t)k*Nact + c] : W2[(size_t)(k-Ksplit)*Nact + c];
    drow[k] = f2b(v);
  }
}

// ---------------------------------------------------------------------------
struct ScanP {
  const unsigned short *WzB, *WhB, *UrT;        // [512][480] K-major bf16
  const unsigned short *XWz, *XWh, *XWr;        // [10240][450] bf16, bias folded in
  const int *edge_src, *edge_dst, *edge_pred, *node_in, *step_eid, *step_v;
  unsigned short *m, *rm, *hb;                  // m/rm [NEDGES+1][480], hb [T*B][450]
  int P, Dn;
};

// Tree-owned scan: 64 blocks x 8 trees, NO cross-block deps, NO grid syncs.
// 1024 thr = 16 waves; wave wv owns output cols [32wv,32wv+32).
// XW rows LDS-staged; B panels software-pipelined global->reg from warm L2.
__global__ __launch_bounds__(1024) void k_scan_tree(ScanP p){
  __shared__ unsigned short A1s[16*AST];   // [s] bf16 (rows 8..15 zero)
  __shared__ unsigned short A2s[16*AST];   // [arm] -> m_new after gate epilogue
  __shared__ float SL[NT*KS];              // f32 pred-sum s
  __shared__ unsigned short sZ[NT*XST], sH[NT*XST], sR[NT*XST];  // staged XW rows
  __shared__ int s_moff[NT], s_src[NT], s_dst[NT], s_pcnt[NT], s_dcnt[NT];
  __shared__ int s_poff[NT][MAXP];
  __shared__ int s_noff[NT][MAXD];

  const int tid = threadIdx.x;
  const int lane = tid & 63, l15 = lane & 15, kh = lane >> 4, ko = kh*8;
  const int wv = tid >> 6;
  const int r0 = blockIdx.x * NT;
  const int P = p.P, Dn = p.Dn;
  const int gr = tid >> 7, gsub = tid & 127;    // gather: 128 threads per tree
  const int c_0 = wv*32 + l15, c_1 = c_0 + 16;  // this lane's two output cols

  const unsigned short* pWz0 = p.WzB + (size_t)c_0*KS;
  const unsigned short* pWz1 = p.WzB + (size_t)c_1*KS;
  const unsigned short* pWh0 = p.WhB + (size_t)c_0*KS;
  const unsigned short* pWh1 = p.WhB + (size_t)c_1*KS;
  const unsigned short* pUr0 = p.UrT + (size_t)c_0*KS;
  const unsigned short* pUr1 = p.UrT + (size_t)c_1*KS;
  const unsigned short* aA1 = A1s + l15*AST;    // A row = tree = l15
  const unsigned short* aA2 = A2s + l15*AST;

  // zero A tiles once (rows 8..15 stay zero forever; pads of rows 0..7 stay zero)
  for (int idx = tid; idx < 16*AST; idx += 1024){ A1s[idx] = 0; A2s[idx] = 0; }

  for (int t = 0; t < T_; ++t){
    __syncthreads();   // (0) prev-step reads of A1s/A2s/meta done
    if (tid < NT){
      int b = r0 + tid;
      int e = p.step_eid[t*B_ + b];
      s_moff[tid] = e*KS;
      s_src[tid] = p.edge_src[e]*H_;
      s_dst[tid] = p.edge_dst[e]*H_;
      int pc = 0;
      for (int q = 0; q < P; ++q){
        int pe = p.edge_pred[e*P + q];
        if (pe != NEDGES) s_poff[tid][pc++] = pe*KS;
      }
      s_pcnt[tid] = pc;
      int v = p.step_v[t*B_ + b];
      int dc = 0;
      for (int d = 0; d < Dn; ++d){
        int ne = p.node_in[v*Dn + d];
        if (ne != NEDGES) s_noff[tid][dc++] = ne*KS;
      }
      s_dcnt[tid] = dc;
    }
    __syncthreads();   // (1) meta ready

    // ---- gather: A1=[s] bf16, A2=[arm] bf16, SL=s f32 (128 thr/tree) ----
    {
      int pc = s_pcnt[gr];
      uint2* d1 = (uint2*)(A1s + gr*AST);
      uint2* d2 = (uint2*)(A2s + gr*AST);
      float* sl = SL + gr*KS;
      for (int j4 = gsub; j4 < 120; j4 += 128){
        float f0=0.f,f1=0.f,f2=0.f,f3=0.f;
        float g0=0.f,g1=0.f,g2=0.f,g3=0.f;
        for (int q = 0; q < pc; ++q){
          int o = s_poff[gr][q] + 4*j4;
          uint2 mv = *(const uint2*)(p.m + o);
          uint2 rv = *(const uint2*)(p.rm + o);
          f0 += b2f((unsigned short)(mv.x & 0xffff)); f1 += b2f((unsigned short)(mv.x >> 16));
          f2 += b2f((unsigned short)(mv.y & 0xffff)); f3 += b2f((unsigned short)(mv.y >> 16));
          g0 += b2f((unsigned short)(rv.x & 0xffff)); g1 += b2f((unsigned short)(rv.x >> 16));
          g2 += b2f((unsigned short)(rv.y & 0xffff)); g3 += b2f((unsigned short)(rv.y >> 16));
        }
        uint2 w1; w1.x = pack2(f0,f1); w1.y = pack2(f2,f3);
        uint2 w2; w2.x = pack2(g0,g1); w2.y = pack2(g2,g3);
        d1[j4] = w1; d2[j4] = w2;
        sl[4*j4] = f0; sl[4*j4+1] = f1; sl[4*j4+2] = f2; sl[4*j4+3] = f3;
      }
    }
    // ---- stage XW rows into LDS (coalesced uint loads) ----
    for (int idx = tid; idx < 3*NT*225; idx += 1024){
      int mat = idx / (NT*225);
      int rem = idx - mat*(NT*225);
      int r = rem / 225, j = rem - r*225;
      int row = (mat == 2) ? s_dst[r] : s_src[r];
      const unsigned short* src = (mat == 0) ? p.XWz : (mat == 1) ? p.XWh : p.XWr;
      unsigned int v = *(const unsigned int*)(src + row + 2*j);
      unsigned short* d = (mat == 0) ? sZ : (mat == 1) ? sH : sR;
      ((unsigned int*)(d + r*XST))[j] = v;
    }
    __syncthreads();   // (2) A tiles + SL + staged XW ready

    // ---- gate K-loop (barrier-free; B software-pipelined from warm L2) ----
    f32x4 accZ0 = {}, accZ1 = {}, accH0 = {}, accH1 = {};
    {
      bf16x8 bz0 = *(const bf16x8*)(pWz0 + ko);
      bf16x8 bz1 = *(const bf16x8*)(pWz1 + ko);
      bf16x8 bh0 = *(const bf16x8*)(pWh0 + ko);
      bf16x8 bh1 = *(const bf16x8*)(pWh1 + ko);
      #pragma unroll
      for (int it = 0; it < 15; ++it){
        bf16x8 nz0, nz1, nh0, nh1;
        if (it < 14){
          nz0 = *(const bf16x8*)(pWz0 + (it+1)*32 + ko);
          nz1 = *(const bf16x8*)(pWz1 + (it+1)*32 + ko);
          nh0 = *(const bf16x8*)(pWh0 + (it+1)*32 + ko);
          nh1 = *(const bf16x8*)(pWh1 + (it+1)*32 + ko);
        }
        bf16x8 a1 = *(const bf16x8*)(aA1 + it*32 + ko);
        bf16x8 a2 = *(const bf16x8*)(aA2 + it*32 + ko);
        accZ0 = __builtin_amdgcn_mfma_f32_16x16x32_bf16(a1,bz0,accZ0,0,0,0);
        accZ1 = __builtin_amdgcn_mfma_f32_16x16x32_bf16(a1,bz1,accZ1,0,0,0);
        accH0 = __builtin_amdgcn_mfma_f32_16x16x32_bf16(a2,bh0,accH0,0,0,0);
        accH1 = __builtin_amdgcn_mfma_f32_16x16x32_bf16(a2,bh1,accH1,0,0,0);
        bz0 = nz0; bz1 = nz1; bh0 = nh0; bh1 = nh1;
      }
    }
    __syncthreads();   // (3) all waves done reading A2s (arm)

    // ---- gate epilogue: m_new -> global m + LDS (A2s); XW from LDS ----
    #pragma unroll
    for (int n = 0; n < 2; ++n){
      int cc = wv*32 + n*16 + l15;
      if (cc < H_){
        f32x4 aZ = n ? accZ1 : accZ0;
        f32x4 aH = n ? accH1 : accH0;
        #pragma unroll
        for (int reg = 0; reg < 4; ++reg){
          int rl = kh*4 + reg;
          if (rl < NT){
            float z  = sigmoidf_(aZ[reg] + b2f(sZ[rl*XST + cc]));
            float th = tanhf   (aH[reg] + b2f(sH[rl*XST + cc]));
            float s_ = SL[rl*KS + cc];
            float mn = (1.f - z)*s_ + z*th;
            unsigned short mb = f2b(mn);
            p.m[s_moff[rl] + cc] = mb;
            A2s[rl*AST + cc] = mb;
          }
        }
      }
    }
    __syncthreads();   // (4) m_new in A2s complete

    // ---- rgate K-loop: R = m_new@Ur (A from LDS, B pipelined) ----
    f32x4 accR0 = {}, accR1 = {};
    {
      bf16x8 u0 = *(const bf16x8*)(pUr0 + ko);
      bf16x8 u1 = *(const bf16x8*)(pUr1 + ko);
      #pragma unroll
      for (int it = 0; it < 15; ++it){
        bf16x8 n0, n1;
        if (it < 14){
          n0 = *(const bf16x8*)(pUr0 + (it+1)*32 + ko);
          n1 = *(const bf16x8*)(pUr1 + (it+1)*32 + ko);
        }
        bf16x8 a = *(const bf16x8*)(aA2 + it*32 + ko);
        accR0 = __builtin_amdgcn_mfma_f32_16x16x32_bf16(a,u0,accR0,0,0,0);
        accR1 = __builtin_amdgcn_mfma_f32_16x16x32_bf16(a,u1,accR1,0,0,0);
        u0 = n0; u1 = n1;
      }
    }

    // ---- rgate epilogue: rm, h-pull (XWr from LDS) ----
    #pragma unroll
    for (int n = 0; n < 2; ++n){
      int cc = wv*32 + n*16 + l15;
      if (cc < H_){
        f32x4 aR = n ? accR1 : accR0;
        #pragma unroll
        for (int reg = 0; reg < 4; ++reg){
          int rl = kh*4 + reg;
          if (rl < NT){
            float r_ = sigmoidf_(aR[reg] + b2f(sR[rl*XST + cc]));
            float mn = b2f(A2s[rl*AST + cc]);
            p.rm[s_moff[rl] + cc] = f2b(r_*mn);
            float h = 0.f;
            int dc = s_dcnt[rl];
            for (int d = 0; d < dc; ++d) h += b2f(p.m[s_noff[rl][d] + cc]);
            p.hb[(size_t)(t*B_ + r0 + rl)*H_ + cc] = f2b(h);
          }
        }
      }
    }
    // loop-top barrier (0) protects meta/A1s/A2s for next step
  }
}

// ---------------------------------------------------------------------------
// MFMA tile core for heads: 64x64 tile, 4 waves (2x2), BK=32, K-major bf16.
__device__ __forceinline__ void mfma_tile_core(
    const unsigned short* __restrict__ A, const unsigned short* __restrict__ BT,
    int K, int gr0, int gc0, int tid,
    unsigned short* __restrict__ As, unsigned short* __restrict__ Bs,
    f32x4 (&acc)[2][2])
{
  const int lane = tid & 63;
  const int w = tid >> 6, wr = w >> 1, wc = w & 1;
  const int l15 = lane & 15, kh = lane >> 4;
  const int sr = tid >> 2, sj = (tid & 3) * 8;
  const size_t arow = (size_t)(gr0 + sr) * K;
  const size_t brow = (size_t)(gc0 + sr) * K;
  for (int kt = 0; kt < K; kt += 32){
    __syncthreads();
    *(float4*)&As[sr*40 + sj] = *(const float4*)&A[arow + kt + sj];
    *(float4*)&Bs[sr*40 + sj] = *(const float4*)&BT[brow + kt + sj];
    __syncthreads();
    bf16x8 a0 = *(const bf16x8*)&As[(wr*32      + l15)*40 + kh*8];
    bf16x8 a1 = *(const bf16x8*)&As[(wr*32 + 16 + l15)*40 + kh*8];
    bf16x8 b0 = *(const bf16x8*)&Bs[(wc*32      + l15)*40 + kh*8];
    bf16x8 b1 = *(const bf16x8*)&Bs[(wc*32 + 16 + l15)*40 + kh*8];
    acc[0][0] = __builtin_amdgcn_mfma_f32_16x16x32_bf16(a0,b0,acc[0][0],0,0,0);
    acc[0][1] = __builtin_amdgcn_mfma_f32_16x16x32_bf16(a0,b1,acc[0][1],0,0,0);
    acc[1][0] = __builtin_amdgcn_mfma_f32_16x16x32_bf16(a1,b0,acc[1][0],0,0,0);
    acc[1][1] = __builtin_amdgcn_mfma_f32_16x16x32_bf16(a1,b1,acc[1][1],0,0,0);
  }
}

// Head GEMM: C = act(A@B + bias); f32 store and/or bf16 store.
__global__ __launch_bounds__(256) void k_head_mfma(
    const unsigned short* __restrict__ A, const unsigned short* __restrict__ BT, int K,
    const float* __restrict__ bias, int Nact, int relu,
    float* __restrict__ outF, int ldF, unsigned short* __restrict__ outB, int ldB)
{
  __shared__ unsigned short As[64*40], Bs[64*40];
  const int tid = threadIdx.x;
  const int gr0 = blockIdx.y*64, gc0 = blockIdx.x*64;
  f32x4 acc[2][2] = {};
  mfma_tile_core(A, BT, K, gr0, gc0, tid, As, Bs, acc);
  const int lane = tid & 63;
  const int w = tid >> 6, wr = w >> 1, wc = w & 1;
  const int l15 = lane & 15, kh = lane >> 4;
  #pragma unroll
  for (int mi = 0; mi < 2; ++mi){
    #pragma unroll
    for (int n = 0; n < 2; ++n){
      int c = gc0 + wc*32 + n*16 + l15;
      float bc = (c < Nact) ? bias[c] : 0.f;
      #pragma unroll
      for (int reg = 0; reg < 4; ++reg){
        int r = gr0 + wr*32 + mi*16 + kh*4 + reg;
        float v = acc[mi][n][reg] + bc;
        if (relu) v = fmaxf(v, 0.f);
        if (outF && c < Nact) outF[(size_t)r*ldF + c] = v;
        if (outB && c < ldB)  outB[(size_t)r*ldB + c] = (c < Nact) ? f2b(v) : (unsigned short)0;
      }
    }
  }
}

// p-head GEMM with fused Us-dot: plog[r] += sum_c relu(acc+bu)*Us[c]
__global__ __launch_bounds__(256) void k_head_p(
    const unsigned short* __restrict__ A, const unsigned short* __restrict__ BT,
    const float* __restrict__ bu_, const float* __restrict__ Us, float* __restrict__ plog)
{
  __shared__ unsigned short As[64*40], Bs[64*40];
  const int tid = threadIdx.x;
  const int gr0 = blockIdx.y*64, gc0 = blockIdx.x*64;
  f32x4 acc[2][2] = {};
  mfma_tile_core(A, BT, 960, gr0, gc0, tid, As, Bs, acc);
  const int lane = tid & 63;
  const int w = tid >> 6, wr = w >> 1, wc = w & 1;
  const int l15 = lane & 15, kh = lane >> 4;
  #pragma unroll
  for (int mi = 0; mi < 2; ++mi){
    float rowsum[4] = {0.f,0.f,0.f,0.f};
    #pragma unroll
    for (int n = 0; n < 2; ++n){
      int c = gc0 + wc*32 + n*16 + l15;
      float uc = 0.f, bc = 0.f;
      if (c < H_){ uc = Us[c]; bc = bu_[c]; }
      #pragma unroll
      for (int reg = 0; reg < 4; ++reg){
        float v = fmaxf(acc[mi][n][reg] + bc, 0.f);
        rowsum[reg] += (c < H_) ? v*uc : 0.f;
      }
    }
    #pragma unroll
    for (int reg = 0; reg < 4; ++reg){
      float p = rowsum[reg];
      p += __shfl_xor(p,1); p += __shfl_xor(p,2);
      p += __shfl_xor(p,4); p += __shfl_xor(p,8);
      if (l15 == 0) atomicAdd(plog + gr0 + wr*32 + mi*16 + kh*4 + reg, p);
    }
  }
}

// ---------------------------------------------------------------------------
// Builders (wave-per-row, vectorized, write pads)
__global__ __launch_bounds__(256) void k_build_Aq(const unsigned short* __restrict__ hb,
    const float* __restrict__ tv, const int* __restrict__ q_rows,
    unsigned short* __restrict__ Aq, int nq){
  int w = blockIdx.x*4 + (threadIdx.x>>6), lane = threadIdx.x & 63;
  int nw = gridDim.x*4;
  for (int i = w; i < nq; i += nw){
    int row = q_rows[i]; int b = row & (B_-1);
    unsigned short* dst = Aq + (size_t)i*512;
    if (row < B_){
      for (int j2 = lane; j2 < 225; j2 += 64) ((unsigned int*)dst)[j2] = 0u;
    } else {
      const unsigned int* src = (const unsigned int*)(hb + (size_t)(row-B_)*H_);
      for (int j2 = lane; j2 < 225; j2 += 64) ((unsigned int*)dst)[j2] = src[j2];
    }
    int k = 450 + lane;
    if (k < 512){
      unsigned short v = 0;
      if (k < 506) v = f2b(tv[b*L_ + (k-450)]);
      dst[k] = v;
    }
  }
}

__global__ __launch_bounds__(256) void k_build_Ap(const unsigned short* __restrict__ hb,
    const unsigned short* __restrict__ xb, const float* __restrict__ tv,
    const int* __restrict__ root_ids, const int* __restrict__ step_v,
    unsigned short* __restrict__ Ap){
  int w = blockIdx.x*4 + (threadIdx.x>>6), lane = threadIdx.x & 63;
  int nw = gridDim.x*4;
  for (int i = w; i < NPROWS; i += nw){
    int b = i & (B_-1);
    unsigned short* dst = Ap + (size_t)i*960;
    int xn = (i < B_) ? root_ids[b] : step_v[i - B_];
    const unsigned int* xr = (const unsigned int*)(xb + (size_t)xn*KS);
    for (int j2 = lane; j2 < 225; j2 += 64) ((unsigned int*)dst)[j2] = xr[j2];
    if (i < B_){
      for (int j2 = lane; j2 < 225; j2 += 64) ((unsigned int*)(dst + 450))[j2] = 0u;
    } else {
      const unsigned int* hr = (const unsigned int*)(hb + (size_t)(i-B_)*H_);
      for (int j2 = lane; j2 < 225; j2 += 64) ((unsigned int*)(dst + 450))[j2] = hr[j2];
    }
    int k = 900 + lane;
    if (k < 960){
      unsigned short v = 0;
      if (k < 956) v = f2b(tv[b*L_ + (k-900)]);
      dst[k] = v;
    }
  }
}

// ---------------------------------------------------------------------------
// q reduce: wave-per-row, register-cached row, shuffle reductions
__global__ __launch_bounds__(256) void k_qreduce2(const float* __restrict__ logits,
    const int* __restrict__ q_tgt, int nq, float* __restrict__ out){
  int w = blockIdx.x*4 + (threadIdx.x>>6), lane = threadIdx.x & 63;
  int nw = gridDim.x*4;
  float qloss = 0.f, qacc = 0.f;
  for (int i = w; i < nq; i += nw){
    const float4* lr4 = (const float4*)(logits + (size_t)i*V_);
    float4 vals[4]; int cnt = 0;
    float mx = -INFINITY; int mi = 0x7fffffff;
    for (int j4 = lane; j4 < 195; j4 += 64){
      float4 v = lr4[j4]; vals[cnt++] = v;
      #pragma unroll
      for (int u = 0; u < 4; ++u){
        float f = ((float*)&v)[u];
        if (f > mx){ mx = f; mi = j4*4 + u; }
      }
    }
    #pragma unroll
    for (int off = 32; off; off >>= 1){
      float omx = __shfl_xor(mx, off); int omi = __shfl_xor(mi, off);
      if (omx > mx || (omx == mx && omi < mi)){ mx = omx; mi = omi; }
    }
    float ps = 0.f; cnt = 0;
    for (int j4 = lane; j4 < 195; j4 += 64){
      float4 v = vals[cnt++];
      ps += expf(v.x-mx) + expf(v.y-mx) + expf(v.z-mx) + expf(v.w-mx);
    }
    #pragma unroll
    for (int off = 32; off; off >>= 1) ps += __shfl_xor(ps, off);
    if (lane == 0){
      int tg = q_tgt[i];
      float lt = logits[(size_t)i*V_ + tg];
      qloss += mx + logf(ps) - lt;
      qacc  += (mi == tg) ? 1.f : 0.f;
    }
  }
  if (lane == 0){
    atomicAdd(out+0, qloss*(1.0f/B_));
    atomicAdd(out+2, qacc *(1.0f/(float)nq));
  }
}

// p final: BCE + acc from plog
__global__ __launch_bounds__(256) void k_pfinal(const float* __restrict__ plog,
    const float* __restrict__ bs, const int* __restrict__ p_tgt, float* __restrict__ out){
  int i = blockIdx.x*256 + threadIdx.x;
  float loss = 0.f, acc = 0.f;
  if (i < NPROWS){
    float pl = plog[i] + bs[0];
    float tgt = (float)p_tgt[i];
    loss = fmaxf(pl, 0.f) + log1pf(expf(-fabsf(pl))) - pl*tgt;
    acc = (((pl > 0.f) ? 1 : 0) == p_tgt[i]) ? 1.f : 0.f;
  }
  #pragma unroll
  for (int off = 32; off; off >>= 1){
    loss += __shfl_xor(loss, off); acc += __shfl_xor(acc, off);
  }
  if ((threadIdx.x & 63) == 0){
    atomicAdd(out+1, loss*(1.0f/B_));
    atomicAdd(out+3, acc *(1.0f/(float)NPROWS));
  }
}

// ---------------------------------------------------------------------------
extern "C" void kernel_launch(void* const* d_in, const int* in_sizes, int n_in,
                              void* d_out, int out_size, void* d_ws, size_t ws_size,
                              hipStream_t stream){
  const float* tree_vec = (const float*)d_in[0];
  const float* emb  = (const float*)d_in[1];
  const float* Wz   = (const float*)d_in[2];
  const float* bz   = (const float*)d_in[3];
  const float* Wh   = (const float*)d_in[4];
  const float* bh   = (const float*)d_in[5];
  const float* Wr   = (const float*)d_in[6];
  const float* Ur   = (const float*)d_in[7];
  const float* br   = (const float*)d_in[8];
  const float* Ww   = (const float*)d_in[9];
  const float* bw   = (const float*)d_in[10];
  const float* Uw   = (const float*)d_in[11];
  const float* bu   = (const float*)d_in[12];
  const float* Wo   = (const float*)d_in[13];
  const float* bo   = (const float*)d_in[14];
  const float* Us   = (const float*)d_in[15];
  const float* bs   = (const float*)d_in[16];
  const int* wid      = (const int*)d_in[17];
  const int* root_ids = (const int*)d_in[18];
  const int* edge_src = (const int*)d_in[19];
  const int* edge_dst = (const int*)d_in[20];
  const int* edge_pred= (const int*)d_in[21];
  const int* node_in  = (const int*)d_in[22];
  const int* step_eid = (const int*)d_in[23];
  const int* step_v   = (const int*)d_in[24];
  const int* q_rows   = (const int*)d_in[25];
  const int* q_tgt    = (const int*)d_in[26];
  const int* p_tgt    = (const int*)d_in[27];
  int P  = in_sizes[21] / NEDGES;  if (P > MAXP) P = MAXP;
  int Dn = in_sizes[22] / NNODES;  if (Dn > MAXD) Dn = MAXD;
  int nq = in_sizes[25];           // 10240

  char* ws = (char*)d_ws;
  // --- layout ---
  const size_t XB_OFF  = 0;                         // bf16 [10240][480] = 9,830,400
  const size_t HB_OFF  = 9830400;                   // bf16 [19456][450] = 17,510,400
  const size_t M_OFF   = 27340800;                  // bf16 [19457][480] (pad 18,678,784)
  const size_t RM_OFF  = M_OFF + 18678784;          // = 46,019,584
  const size_t WZB_OFF = RM_OFF + 18678784;         // = 64,698,368  bf16 [512][480]
  const size_t WHB_OFF = WZB_OFF + 491520;
  const size_t URT_OFF = WHB_OFF + 491520;
  const size_t WZTOP_OFF = URT_OFF + 491520;        // = 66,172,928
  const size_t WHTOP_OFF = WZTOP_OFF + 491520;
  const size_t WRT_OFF   = WHTOP_OFF + 491520;
  const size_t WWT_OFF = WRT_OFF + 491520;          // = 67,647,488  bf16 [512][512]
  const size_t UWT_OFF = WWT_OFF + 524288;          // bf16 [512][960]
  const size_t WOT_OFF = UWT_OFF + 983040;          // bf16 [832][512]
  const size_t XWZ_OFF = WOT_OFF + 851968;          // = 70,006,784  bf16 [10240][450]
  const size_t XWH_OFF = XWZ_OFF + 9216000;
  const size_t XWR_OFF = XWH_OFF + 9216000;         // ends 97,654,784
  // overlays after scan:
  const size_t LQ_OFF  = M_OFF;                     // f32 [10240][780] (fits M+RM)
  const size_t AQ_OFF  = XWZ_OFF;                   // bf16 [10240][512] (XW dead post-scan)
  const size_t HQB_OFF = AQ_OFF + 10485760;
  const size_t PL_OFF  = HQB_OFF + 10485760;        // f32 [19968]
  const size_t AP_OFF  = M_OFF;                     // bf16 [19968][960] (M..weights dead)

  unsigned short* xb = (unsigned short*)(ws + XB_OFF);
  unsigned short* hb = (unsigned short*)(ws + HB_OFF);
  unsigned short* m_ = (unsigned short*)(ws + M_OFF);
  unsigned short* rm = (unsigned short*)(ws + RM_OFF);
  unsigned short* WzB = (unsigned short*)(ws + WZB_OFF);
  unsigned short* WhB = (unsigned short*)(ws + WHB_OFF);
  unsigned short* UrT = (unsigned short*)(ws + URT_OFF);
  unsigned short* WzTop = (unsigned short*)(ws + WZTOP_OFF);
  unsigned short* WhTop = (unsigned short*)(ws + WHTOP_OFF);
  unsigned short* WrT = (unsigned short*)(ws + WRT_OFF);
  unsigned short* WwT = (unsigned short*)(ws + WWT_OFF);
  unsigned short* UwT = (unsigned short*)(ws + UWT_OFF);
  unsigned short* WoT = (unsigned short*)(ws + WOT_OFF);
  unsigned short* XWz = (unsigned short*)(ws + XWZ_OFF);
  unsigned short* XWh = (unsigned short*)(ws + XWH_OFF);
  unsigned short* XWr = (unsigned short*)(ws + XWR_OFF);

  hipMemsetAsync(ws + M_OFF, 0, 2*18678784ull, stream);   // m, rm (incl sentinel+pads)
  hipMemsetAsync(d_out, 0, (size_t)out_size*sizeof(float), stream);

  k_gather_xb<<<2560, 256, 0, stream>>>(emb, wid, xb);

  // scan weights: bottom halves (K rows 450..899) + Ur; top halves for XW precompute
  k_wt<<<512, 256, 0, stream>>>(Wz + 450*450, Wz, 450, 450, 450, WzB, KS);
  k_wt<<<512, 256, 0, stream>>>(Wh + 450*450, Wh, 450, 450, 450, WhB, KS);
  k_wt<<<512, 256, 0, stream>>>(Ur, Ur, 450, 450, 450, UrT, KS);
  k_wt<<<512, 256, 0, stream>>>(Wz, Wz, 450, 450, 450, WzTop, KS);
  k_wt<<<512, 256, 0, stream>>>(Wh, Wh, 450, 450, 450, WhTop, KS);
  k_wt<<<512, 256, 0, stream>>>(Wr, Wr, 450, 450, 450, WrT, KS);
  k_wt<<<512, 256, 0, stream>>>(Ww, Ww, 506, 506, 450, WwT, 512);
  k_wt<<<512, 256, 0, stream>>>(Uw, Uw, 956, 956, 450, UwT, 960);
  k_wt<<<832, 256, 0, stream>>>(Wo, Wo, 450, 450, 780, WoT, 512);

  // XW precompute (bias folded): XWz = xb@WzTop + bz, etc.  [10240][450] bf16
  k_head_mfma<<<dim3(8,160), 256, 0, stream>>>(xb, WzTop, KS, bz, H_, 0, nullptr, 0, XWz, H_);
  k_head_mfma<<<dim3(8,160), 256, 0, stream>>>(xb, WhTop, KS, bh, H_, 0, nullptr, 0, XWh, H_);
  k_head_mfma<<<dim3(8,160), 256, 0, stream>>>(xb, WrT,   KS, br, H_, 0, nullptr, 0, XWr, H_);

  // ---- tree-owned fused scan: 64 blocks x 8 trees, no cross-block deps ----
  ScanP sp;
  sp.WzB = WzB; sp.WhB = WhB; sp.UrT = UrT;
  sp.XWz = XWz; sp.XWh = XWh; sp.XWr = XWr;
  sp.edge_src = edge_src; sp.edge_dst = edge_dst; sp.edge_pred = edge_pred;
  sp.node_in = node_in; sp.step_eid = step_eid; sp.step_v = step_v;
  sp.m = m_; sp.rm = rm; sp.hb = hb;
  sp.P = P; sp.Dn = Dn;
  k_scan_tree<<<64, 1024, 0, stream>>>(sp);

  // ---- q head ----
  unsigned short* Aq  = (unsigned short*)(ws + AQ_OFF);
  float* logitsq      = (float*)(ws + LQ_OFF);
  unsigned short* hqb = (unsigned short*)(ws + HQB_OFF);
  float* plog         = (float*)(ws + PL_OFF);
  hipMemsetAsync(plog, 0, (size_t)NPROWS*4, stream);

  k_build_Aq<<<640, 256, 0, stream>>>(hb, tree_vec, q_rows, Aq, nq);
  k_head_mfma<<<dim3(8, nq/64), 256, 0, stream>>>(Aq, WwT, 512, bw, H_, 1,
      nullptr, 0, hqb, 512);
  k_head_mfma<<<dim3(13, nq/64), 256, 0, stream>>>(hqb, WoT, 512, bo, V_, 0,
      logitsq, V_, nullptr, 0);
  k_qreduce2<<<320, 256, 0, stream>>>(logitsq, q_tgt, nq, (float*)d_out);

  // ---- p head ----
  unsigned short* Ap = (unsigned short*)(ws + AP_OFF);
  k_build_Ap<<<1248, 256, 0, stream>>>(hb, xb, tree_vec, root_ids, step_v, Ap);
  k_head_p<<<dim3(8, NPROWS/64), 256, 0, stream>>>(Ap, UwT, bu, Us, plog);
  k_pfinal<<<78, 256, 0, stream>>>(plog, bs, p_tgt, (float*)d_out);
}

// Round 10
// 1564.922 us; speedup vs baseline: 2.6178x; 1.0528x over previous
//
#include <hip/hip_runtime.h>
#include <math.h>

#define B_ 512
#define N_ 20
#define H_ 450
#define L_ 56
#define V_ 780
#define T_ 38
#define NNODES (B_*N_)        // 10240
#define NEDGES (B_*2*(N_-1))  // 19456
#define NPROWS ((T_+1)*B_)    // 19968
#define MAXP 8
#define MAXD 8
#define KS 480                // scan K pad (450 -> 480 = 15*32); also m/rm row stride
#define AST 488               // A-tile LDS row stride in shorts (976B, 16B-aligned)
#define NT 8                  // trees per block
#define XST 456               // XW-stage LDS row stride in shorts (912B)

typedef __attribute__((ext_vector_type(8))) short bf16x8;
typedef __attribute__((ext_vector_type(4))) float f32x4;

__device__ __forceinline__ float sigmoidf_(float v){ return 1.0f/(1.0f+expf(-v)); }

__device__ __forceinline__ unsigned short f2b(float x){
  unsigned int u = __float_as_uint(x);
  unsigned int r = (u + 0x7fffu + ((u >> 16) & 1u)) >> 16;
  return (unsigned short)r;
}
__device__ __forceinline__ float b2f(unsigned short v){
  return __uint_as_float((unsigned int)v << 16);
}
__device__ __forceinline__ unsigned int pack2(float lo, float hi){
  return (unsigned int)f2b(lo) | ((unsigned int)f2b(hi) << 16);
}

// ---------------------------------------------------------------------------
// xb[i][:] = bf16(emb[wid[i]][:]), K-padded to 480
__global__ __launch_bounds__(256) void k_gather_xb(const float* __restrict__ emb,
    const int* __restrict__ wid, unsigned short* __restrict__ xb){
  int w = blockIdx.x*4 + (threadIdx.x>>6), lane = threadIdx.x & 63;
  if (w >= NNODES) return;
  const float2* src = (const float2*)(emb + (size_t)wid[w]*H_);
  unsigned int* dst = (unsigned int*)(xb + (size_t)w*KS);
  for (int j2 = lane; j2 < 240; j2 += 64){
    unsigned int v = 0;
    if (j2 < 225){ float2 f = src[j2]; v = pack2(f.x, f.y); }
    dst[j2] = v;
  }
}

// Transpose+convert weight to K-major bf16 with zero padding.
__global__ void k_wt(const float* __restrict__ W1, const float* __restrict__ W2,
                     int Ksplit, int Kact, int Nact, unsigned short* __restrict__ dst, int Kpad){
  int c = blockIdx.x;
  unsigned short* drow = dst + (size_t)c*Kpad;
  for (int k = threadIdx.x; k < Kpad; k += blockDim.x){
    float v = 0.f;
    if (c < Nact && k < Kact)
      v = (k < Ksplit) ? W1[(size_t)k*Nact + c] : W2[(size_t)(k-Ksplit)*Nact + c];
    drow[k] = f2b(v);
  }
}

// ---------------------------------------------------------------------------
struct ScanP {
  const unsigned short *WzB, *WhB, *UrT;        // [512][480] K-major bf16
  const unsigned short *XWz, *XWh, *XWr;        // [10240][450] bf16, bias folded in
  const int *edge_src, *edge_dst, *edge_pred, *node_in, *step_eid, *step_v;
  unsigned short *m, *rm, *hb;                  // m/rm [NEDGES+1][480], hb [T*B][450]
  int P, Dn;
};

// Tree-owned scan: 64 blocks x 8 trees, no cross-block deps.
// R10: VGPR budget 128 (launch_bounds ,4), 3-deep B prefetch ring, all-step meta
// preload (4 barriers/step), SL dropped (bf16 s from A1s).
__global__ __launch_bounds__(1024, 4) void k_scan_tree(ScanP p){
  __shared__ unsigned short A1s[16*AST];   // [s] bf16 (rows 8..15 zero)
  __shared__ unsigned short A2s[16*AST];   // [arm] -> m_new after gate epilogue
  __shared__ unsigned short sZ[NT*XST], sH[NT*XST], sR[NT*XST];  // staged XW rows
  __shared__ int s_moff[T_][NT], s_srcO[T_][NT], s_dstO[T_][NT];
  __shared__ int s_poff[T_][NT][MAXP];
  __shared__ int s_noff[T_][NT][MAXD];
  __shared__ short s_pcnt[T_][NT], s_dcnt[T_][NT];

  const int tid = threadIdx.x;
  const int lane = tid & 63, l15 = lane & 15, kh = lane >> 4, ko = kh*8;
  const int wv = tid >> 6;
  const int r0 = blockIdx.x * NT;
  const int P = p.P, Dn = p.Dn;
  const int gr = tid >> 7, gsub = tid & 127;    // gather: 128 threads per tree
  const int c_0 = wv*32 + l15, c_1 = c_0 + 16;  // this lane's two output cols

  const unsigned short* pWz0 = p.WzB + (size_t)c_0*KS;
  const unsigned short* pWz1 = p.WzB + (size_t)c_1*KS;
  const unsigned short* pWh0 = p.WhB + (size_t)c_0*KS;
  const unsigned short* pWh1 = p.WhB + (size_t)c_1*KS;
  const unsigned short* pUr0 = p.UrT + (size_t)c_0*KS;
  const unsigned short* pUr1 = p.UrT + (size_t)c_1*KS;
  const unsigned short* aA1 = A1s + l15*AST;    // A row = tree = l15
  const unsigned short* aA2 = A2s + l15*AST;

  // one-time: zero A tiles (rows 8..15 + pads stay zero forever)
  for (int idx = tid; idx < 16*AST; idx += 1024){ A1s[idx] = 0; A2s[idx] = 0; }
  // one-time: preload ALL per-step metadata (compacted pred/node lists)
  for (int idx = tid; idx < T_*NT; idx += 1024){
    int t = idx >> 3, rl = idx & 7;
    int e = p.step_eid[t*B_ + r0 + rl];
    s_moff[t][rl] = e*KS;
    s_srcO[t][rl] = p.edge_src[e]*H_;
    s_dstO[t][rl] = p.edge_dst[e]*H_;
    int pc = 0;
    for (int q = 0; q < P; ++q){
      int pe = p.edge_pred[e*P + q];
      if (pe != NEDGES) s_poff[t][rl][pc++] = pe*KS;
    }
    s_pcnt[t][rl] = (short)pc;
    int v = p.step_v[t*B_ + r0 + rl];
    int dc = 0;
    for (int d = 0; d < Dn; ++d){
      int ne = p.node_in[v*Dn + d];
      if (ne != NEDGES) s_noff[t][rl][dc++] = ne*KS;
    }
    s_dcnt[t][rl] = (short)dc;
  }
  __syncthreads();

  for (int t = 0; t < T_; ++t){
    // ---- prefetch gate-B iters 0..2 (latency overlaps gather below) ----
    bf16x8 bz0[3], bz1[3], bh0[3], bh1[3];
    #pragma unroll
    for (int i = 0; i < 3; ++i){
      bz0[i] = *(const bf16x8*)(pWz0 + i*32 + ko);
      bz1[i] = *(const bf16x8*)(pWz1 + i*32 + ko);
      bh0[i] = *(const bf16x8*)(pWh0 + i*32 + ko);
      bh1[i] = *(const bf16x8*)(pWh1 + i*32 + ko);
    }

    // ---- gather: A1=[s] bf16, A2=[arm] bf16 ----
    {
      int pc = s_pcnt[t][gr];
      uint2* d1 = (uint2*)(A1s + gr*AST);
      uint2* d2 = (uint2*)(A2s + gr*AST);
      for (int j4 = gsub; j4 < 120; j4 += 128){
        float f0=0.f,f1=0.f,f2=0.f,f3=0.f;
        float g0=0.f,g1=0.f,g2=0.f,g3=0.f;
        for (int q = 0; q < pc; ++q){
          int o = s_poff[t][gr][q] + 4*j4;
          uint2 mv = *(const uint2*)(p.m + o);
          uint2 rv = *(const uint2*)(p.rm + o);
          f0 += b2f((unsigned short)(mv.x & 0xffff)); f1 += b2f((unsigned short)(mv.x >> 16));
          f2 += b2f((unsigned short)(mv.y & 0xffff)); f3 += b2f((unsigned short)(mv.y >> 16));
          g0 += b2f((unsigned short)(rv.x & 0xffff)); g1 += b2f((unsigned short)(rv.x >> 16));
          g2 += b2f((unsigned short)(rv.y & 0xffff)); g3 += b2f((unsigned short)(rv.y >> 16));
        }
        uint2 w1; w1.x = pack2(f0,f1); w1.y = pack2(f2,f3);
        uint2 w2; w2.x = pack2(g0,g1); w2.y = pack2(g2,g3);
        d1[j4] = w1; d2[j4] = w2;
      }
    }
    // ---- stage XW rows into LDS (coalesced uint loads) ----
    for (int idx = tid; idx < 3*NT*225; idx += 1024){
      int mat = idx / (NT*225);
      int rem = idx - mat*(NT*225);
      int r = rem / 225, j = rem - r*225;
      int row = (mat == 2) ? s_dstO[t][r] : s_srcO[t][r];
      const unsigned short* src = (mat == 0) ? p.XWz : (mat == 1) ? p.XWh : p.XWr;
      unsigned int v = *(const unsigned int*)(src + row + 2*j);
      unsigned short* d = (mat == 0) ? sZ : (mat == 1) ? sH : sR;
      ((unsigned int*)(d + r*XST))[j] = v;
    }
    __syncthreads();   // (A) A tiles + staged XW ready (also drains prefetch)

    // ---- gate K-loop: 3-deep ring prefetch, barrier-free ----
    f32x4 accZ0 = {}, accZ1 = {}, accH0 = {}, accH1 = {};
    #pragma unroll
    for (int it = 0; it < 15; ++it){
      const int s = it % 3;
      bf16x8 a1 = *(const bf16x8*)(aA1 + it*32 + ko);
      bf16x8 a2 = *(const bf16x8*)(aA2 + it*32 + ko);
      accZ0 = __builtin_amdgcn_mfma_f32_16x16x32_bf16(a1, bz0[s], accZ0, 0,0,0);
      accZ1 = __builtin_amdgcn_mfma_f32_16x16x32_bf16(a1, bz1[s], accZ1, 0,0,0);
      accH0 = __builtin_amdgcn_mfma_f32_16x16x32_bf16(a2, bh0[s], accH0, 0,0,0);
      accH1 = __builtin_amdgcn_mfma_f32_16x16x32_bf16(a2, bh1[s], accH1, 0,0,0);
      if (it + 3 < 15){
        bz0[s] = *(const bf16x8*)(pWz0 + (it+3)*32 + ko);
        bz1[s] = *(const bf16x8*)(pWz1 + (it+3)*32 + ko);
        bh0[s] = *(const bf16x8*)(pWh0 + (it+3)*32 + ko);
        bh1[s] = *(const bf16x8*)(pWh1 + (it+3)*32 + ko);
      }
    }
    __syncthreads();   // (B) all waves done reading A2s (arm)

    // ---- prefetch rgate-B iters 0..2 (latency overlaps epilogue) ----
    bf16x8 bu0[3], bu1[3];
    #pragma unroll
    for (int i = 0; i < 3; ++i){
      bu0[i] = *(const bf16x8*)(pUr0 + i*32 + ko);
      bu1[i] = *(const bf16x8*)(pUr1 + i*32 + ko);
    }

    // ---- gate epilogue: m_new -> global m + LDS (A2s); XW + s from LDS ----
    #pragma unroll
    for (int n = 0; n < 2; ++n){
      int cc = wv*32 + n*16 + l15;
      if (cc < H_){
        f32x4 aZ = n ? accZ1 : accZ0;
        f32x4 aH = n ? accH1 : accH0;
        #pragma unroll
        for (int reg = 0; reg < 4; ++reg){
          int rl = kh*4 + reg;
          if (rl < NT){
            float z  = sigmoidf_(aZ[reg] + b2f(sZ[rl*XST + cc]));
            float th = tanhf   (aH[reg] + b2f(sH[rl*XST + cc]));
            float s_ = b2f(A1s[rl*AST + cc]);
            float mn = (1.f - z)*s_ + z*th;
            unsigned short mb = f2b(mn);
            p.m[s_moff[t][rl] + cc] = mb;
            A2s[rl*AST + cc] = mb;
          }
        }
      }
    }
    __syncthreads();   // (C) m_new in A2s complete (drains bu prefetch too)

    // ---- rgate K-loop: R = m_new@Ur (A from LDS, 3-deep B ring) ----
    f32x4 accR0 = {}, accR1 = {};
    #pragma unroll
    for (int it = 0; it < 15; ++it){
      const int s = it % 3;
      bf16x8 a = *(const bf16x8*)(aA2 + it*32 + ko);
      accR0 = __builtin_amdgcn_mfma_f32_16x16x32_bf16(a, bu0[s], accR0, 0,0,0);
      accR1 = __builtin_amdgcn_mfma_f32_16x16x32_bf16(a, bu1[s], accR1, 0,0,0);
      if (it + 3 < 15){
        bu0[s] = *(const bf16x8*)(pUr0 + (it+3)*32 + ko);
        bu1[s] = *(const bf16x8*)(pUr1 + (it+3)*32 + ko);
      }
    }

    // ---- rgate epilogue: rm, h-pull (XWr from LDS) ----
    #pragma unroll
    for (int n = 0; n < 2; ++n){
      int cc = wv*32 + n*16 + l15;
      if (cc < H_){
        f32x4 aR = n ? accR1 : accR0;
        #pragma unroll
        for (int reg = 0; reg < 4; ++reg){
          int rl = kh*4 + reg;
          if (rl < NT){
            float r_ = sigmoidf_(aR[reg] + b2f(sR[rl*XST + cc]));
            float mn = b2f(A2s[rl*AST + cc]);
            p.rm[s_moff[t][rl] + cc] = f2b(r_*mn);
            float h = 0.f;
            int dc = s_dcnt[t][rl];
            for (int d = 0; d < dc; ++d) h += b2f(p.m[s_noff[t][rl][d] + cc]);
            p.hb[(size_t)(t*B_ + r0 + rl)*H_ + cc] = f2b(h);
          }
        }
      }
    }
    __syncthreads();   // (D) reads of A1s/A2s/XW done before next gather
  }
}

// ---------------------------------------------------------------------------
// MFMA tile core for heads: 64x64 tile, 4 waves (2x2), BK=32, K-major bf16.
__device__ __forceinline__ void mfma_tile_core(
    const unsigned short* __restrict__ A, const unsigned short* __restrict__ BT,
    int K, int gr0, int gc0, int tid,
    unsigned short* __restrict__ As, unsigned short* __restrict__ Bs,
    f32x4 (&acc)[2][2])
{
  const int lane = tid & 63;
  const int w = tid >> 6, wr = w >> 1, wc = w & 1;
  const int l15 = lane & 15, kh = lane >> 4;
  const int sr = tid >> 2, sj = (tid & 3) * 8;
  const size_t arow = (size_t)(gr0 + sr) * K;
  const size_t brow = (size_t)(gc0 + sr) * K;
  for (int kt = 0; kt < K; kt += 32){
    __syncthreads();
    *(float4*)&As[sr*40 + sj] = *(const float4*)&A[arow + kt + sj];
    *(float4*)&Bs[sr*40 + sj] = *(const float4*)&BT[brow + kt + sj];
    __syncthreads();
    bf16x8 a0 = *(const bf16x8*)&As[(wr*32      + l15)*40 + kh*8];
    bf16x8 a1 = *(const bf16x8*)&As[(wr*32 + 16 + l15)*40 + kh*8];
    bf16x8 b0 = *(const bf16x8*)&Bs[(wc*32      + l15)*40 + kh*8];
    bf16x8 b1 = *(const bf16x8*)&Bs[(wc*32 + 16 + l15)*40 + kh*8];
    acc[0][0] = __builtin_amdgcn_mfma_f32_16x16x32_bf16(a0,b0,acc[0][0],0,0,0);
    acc[0][1] = __builtin_amdgcn_mfma_f32_16x16x32_bf16(a0,b1,acc[0][1],0,0,0);
    acc[1][0] = __builtin_amdgcn_mfma_f32_16x16x32_bf16(a1,b0,acc[1][0],0,0,0);
    acc[1][1] = __builtin_amdgcn_mfma_f32_16x16x32_bf16(a1,b1,acc[1][1],0,0,0);
  }
}

// Head GEMM: C = act(A@B + bias); f32 store and/or bf16 store.
__global__ __launch_bounds__(256) void k_head_mfma(
    const unsigned short* __restrict__ A, const unsigned short* __restrict__ BT, int K,
    const float* __restrict__ bias, int Nact, int relu,
    float* __restrict__ outF, int ldF, unsigned short* __restrict__ outB, int ldB)
{
  __shared__ unsigned short As[64*40], Bs[64*40];
  const int tid = threadIdx.x;
  const int gr0 = blockIdx.y*64, gc0 = blockIdx.x*64;
  f32x4 acc[2][2] = {};
  mfma_tile_core(A, BT, K, gr0, gc0, tid, As, Bs, acc);
  const int lane = tid & 63;
  const int w = tid >> 6, wr = w >> 1, wc = w & 1;
  const int l15 = lane & 15, kh = lane >> 4;
  #pragma unroll
  for (int mi = 0; mi < 2; ++mi){
    #pragma unroll
    for (int n = 0; n < 2; ++n){
      int c = gc0 + wc*32 + n*16 + l15;
      float bc = (c < Nact) ? bias[c] : 0.f;
      #pragma unroll
      for (int reg = 0; reg < 4; ++reg){
        int r = gr0 + wr*32 + mi*16 + kh*4 + reg;
        float v = acc[mi][n][reg] + bc;
        if (relu) v = fmaxf(v, 0.f);
        if (outF && c < Nact) outF[(size_t)r*ldF + c] = v;
        if (outB && c < ldB)  outB[(size_t)r*ldB + c] = (c < Nact) ? f2b(v) : (unsigned short)0;
      }
    }
  }
}

// p-head GEMM with fused Us-dot: plog[r] += sum_c relu(acc+bu)*Us[c]
__global__ __launch_bounds__(256) void k_head_p(
    const unsigned short* __restrict__ A, const unsigned short* __restrict__ BT,
    const float* __restrict__ bu_, const float* __restrict__ Us, float* __restrict__ plog)
{
  __shared__ unsigned short As[64*40], Bs[64*40];
  const int tid = threadIdx.x;
  const int gr0 = blockIdx.y*64, gc0 = blockIdx.x*64;
  f32x4 acc[2][2] = {};
  mfma_tile_core(A, BT, 960, gr0, gc0, tid, As, Bs, acc);
  const int lane = tid & 63;
  const int w = tid >> 6, wr = w >> 1, wc = w & 1;
  const int l15 = lane & 15, kh = lane >> 4;
  #pragma unroll
  for (int mi = 0; mi < 2; ++mi){
    float rowsum[4] = {0.f,0.f,0.f,0.f};
    #pragma unroll
    for (int n = 0; n < 2; ++n){
      int c = gc0 + wc*32 + n*16 + l15;
      float uc = 0.f, bc = 0.f;
      if (c < H_){ uc = Us[c]; bc = bu_[c]; }
      #pragma unroll
      for (int reg = 0; reg < 4; ++reg){
        float v = fmaxf(acc[mi][n][reg] + bc, 0.f);
        rowsum[reg] += (c < H_) ? v*uc : 0.f;
      }
    }
    #pragma unroll
    for (int reg = 0; reg < 4; ++reg){
      float p = rowsum[reg];
      p += __shfl_xor(p,1); p += __shfl_xor(p,2);
      p += __shfl_xor(p,4); p += __shfl_xor(p,8);
      if (l15 == 0) atomicAdd(plog + gr0 + wr*32 + mi*16 + kh*4 + reg, p);
    }
  }
}

// ---------------------------------------------------------------------------
// Builders (wave-per-row, vectorized, write pads)
__global__ __launch_bounds__(256) void k_build_Aq(const unsigned short* __restrict__ hb,
    const float* __restrict__ tv, const int* __restrict__ q_rows,
    unsigned short* __restrict__ Aq, int nq){
  int w = blockIdx.x*4 + (threadIdx.x>>6), lane = threadIdx.x & 63;
  int nw = gridDim.x*4;
  for (int i = w; i < nq; i += nw){
    int row = q_rows[i]; int b = row & (B_-1);
    unsigned short* dst = Aq + (size_t)i*512;
    if (row < B_){
      for (int j2 = lane; j2 < 225; j2 += 64) ((unsigned int*)dst)[j2] = 0u;
    } else {
      const unsigned int* src = (const unsigned int*)(hb + (size_t)(row-B_)*H_);
      for (int j2 = lane; j2 < 225; j2 += 64) ((unsigned int*)dst)[j2] = src[j2];
    }
    int k = 450 + lane;
    if (k < 512){
      unsigned short v = 0;
      if (k < 506) v = f2b(tv[b*L_ + (k-450)]);
      dst[k] = v;
    }
  }
}

__global__ __launch_bounds__(256) void k_build_Ap(const unsigned short* __restrict__ hb,
    const unsigned short* __restrict__ xb, const float* __restrict__ tv,
    const int* __restrict__ root_ids, const int* __restrict__ step_v,
    unsigned short* __restrict__ Ap){
  int w = blockIdx.x*4 + (threadIdx.x>>6), lane = threadIdx.x & 63;
  int nw = gridDim.x*4;
  for (int i = w; i < NPROWS; i += nw){
    int b = i & (B_-1);
    unsigned short* dst = Ap + (size_t)i*960;
    int xn = (i < B_) ? root_ids[b] : step_v[i - B_];
    const unsigned int* xr = (const unsigned int*)(xb + (size_t)xn*KS);
    for (int j2 = lane; j2 < 225; j2 += 64) ((unsigned int*)dst)[j2] = xr[j2];
    if (i < B_){
      for (int j2 = lane; j2 < 225; j2 += 64) ((unsigned int*)(dst + 450))[j2] = 0u;
    } else {
      const unsigned int* hr = (const unsigned int*)(hb + (size_t)(i-B_)*H_);
      for (int j2 = lane; j2 < 225; j2 += 64) ((unsigned int*)(dst + 450))[j2] = hr[j2];
    }
    int k = 900 + lane;
    if (k < 960){
      unsigned short v = 0;
      if (k < 956) v = f2b(tv[b*L_ + (k-900)]);
      dst[k] = v;
    }
  }
}

// ---------------------------------------------------------------------------
// q reduce: wave-per-row, register-cached row, shuffle reductions
__global__ __launch_bounds__(256) void k_qreduce2(const float* __restrict__ logits,
    const int* __restrict__ q_tgt, int nq, float* __restrict__ out){
  int w = blockIdx.x*4 + (threadIdx.x>>6), lane = threadIdx.x & 63;
  int nw = gridDim.x*4;
  float qloss = 0.f, qacc = 0.f;
  for (int i = w; i < nq; i += nw){
    const float4* lr4 = (const float4*)(logits + (size_t)i*V_);
    float4 vals[4]; int cnt = 0;
    float mx = -INFINITY; int mi = 0x7fffffff;
    for (int j4 = lane; j4 < 195; j4 += 64){
      float4 v = lr4[j4]; vals[cnt++] = v;
      #pragma unroll
      for (int u = 0; u < 4; ++u){
        float f = ((float*)&v)[u];
        if (f > mx){ mx = f; mi = j4*4 + u; }
      }
    }
    #pragma unroll
    for (int off = 32; off; off >>= 1){
      float omx = __shfl_xor(mx, off); int omi = __shfl_xor(mi, off);
      if (omx > mx || (omx == mx && omi < mi)){ mx = omx; mi = omi; }
    }
    float ps = 0.f; cnt = 0;
    for (int j4 = lane; j4 < 195; j4 += 64){
      float4 v = vals[cnt++];
      ps += expf(v.x-mx) + expf(v.y-mx) + expf(v.z-mx) + expf(v.w-mx);
    }
    #pragma unroll
    for (int off = 32; off; off >>= 1) ps += __shfl_xor(ps, off);
    if (lane == 0){
      int tg = q_tgt[i];
      float lt = logits[(size_t)i*V_ + tg];
      qloss += mx + logf(ps) - lt;
      qacc  += (mi == tg) ? 1.f : 0.f;
    }
  }
  if (lane == 0){
    atomicAdd(out+0, qloss*(1.0f/B_));
    atomicAdd(out+2, qacc *(1.0f/(float)nq));
  }
}

// p final: BCE + acc from plog
__global__ __launch_bounds__(256) void k_pfinal(const float* __restrict__ plog,
    const float* __restrict__ bs, const int* __restrict__ p_tgt, float* __restrict__ out){
  int i = blockIdx.x*256 + threadIdx.x;
  float loss = 0.f, acc = 0.f;
  if (i < NPROWS){
    float pl = plog[i] + bs[0];
    float tgt = (float)p_tgt[i];
    loss = fmaxf(pl, 0.f) + log1pf(expf(-fabsf(pl))) - pl*tgt;
    acc = (((pl > 0.f) ? 1 : 0) == p_tgt[i]) ? 1.f : 0.f;
  }
  #pragma unroll
  for (int off = 32; off; off >>= 1){
    loss += __shfl_xor(loss, off); acc += __shfl_xor(acc, off);
  }
  if ((threadIdx.x & 63) == 0){
    atomicAdd(out+1, loss*(1.0f/B_));
    atomicAdd(out+3, acc *(1.0f/(float)NPROWS));
  }
}

// ---------------------------------------------------------------------------
extern "C" void kernel_launch(void* const* d_in, const int* in_sizes, int n_in,
                              void* d_out, int out_size, void* d_ws, size_t ws_size,
                              hipStream_t stream){
  const float* tree_vec = (const float*)d_in[0];
  const float* emb  = (const float*)d_in[1];
  const float* Wz   = (const float*)d_in[2];
  const float* bz   = (const float*)d_in[3];
  const float* Wh   = (const float*)d_in[4];
  const float* bh   = (const float*)d_in[5];
  const float* Wr   = (const float*)d_in[6];
  const float* Ur   = (const float*)d_in[7];
  const float* br   = (const float*)d_in[8];
  const float* Ww   = (const float*)d_in[9];
  const float* bw   = (const float*)d_in[10];
  const float* Uw   = (const float*)d_in[11];
  const float* bu   = (const float*)d_in[12];
  const float* Wo   = (const float*)d_in[13];
  const float* bo   = (const float*)d_in[14];
  const float* Us   = (const float*)d_in[15];
  const float* bs   = (const float*)d_in[16];
  const int* wid      = (const int*)d_in[17];
  const int* root_ids = (const int*)d_in[18];
  const int* edge_src = (const int*)d_in[19];
  const int* edge_dst = (const int*)d_in[20];
  const int* edge_pred= (const int*)d_in[21];
  const int* node_in  = (const int*)d_in[22];
  const int* step_eid = (const int*)d_in[23];
  const int* step_v   = (const int*)d_in[24];
  const int* q_rows   = (const int*)d_in[25];
  const int* q_tgt    = (const int*)d_in[26];
  const int* p_tgt    = (const int*)d_in[27];
  int P  = in_sizes[21] / NEDGES;  if (P > MAXP) P = MAXP;
  int Dn = in_sizes[22] / NNODES;  if (Dn > MAXD) Dn = MAXD;
  int nq = in_sizes[25];           // 10240

  char* ws = (char*)d_ws;
  // --- layout ---
  const size_t XB_OFF  = 0;                         // bf16 [10240][480] = 9,830,400
  const size_t HB_OFF  = 9830400;                   // bf16 [19456][450] = 17,510,400
  const size_t M_OFF   = 27340800;                  // bf16 [19457][480] (pad 18,678,784)
  const size_t RM_OFF  = M_OFF + 18678784;          // = 46,019,584
  const size_t WZB_OFF = RM_OFF + 18678784;         // = 64,698,368  bf16 [512][480]
  const size_t WHB_OFF = WZB_OFF + 491520;
  const size_t URT_OFF = WHB_OFF + 491520;
  const size_t WZTOP_OFF = URT_OFF + 491520;        // = 66,172,928
  const size_t WHTOP_OFF = WZTOP_OFF + 491520;
  const size_t WRT_OFF   = WHTOP_OFF + 491520;
  const size_t WWT_OFF = WRT_OFF + 491520;          // = 67,647,488  bf16 [512][512]
  const size_t UWT_OFF = WWT_OFF + 524288;          // bf16 [512][960]
  const size_t WOT_OFF = UWT_OFF + 983040;          // bf16 [832][512]
  const size_t XWZ_OFF = WOT_OFF + 851968;          // = 70,006,784  bf16 [10240][450]
  const size_t XWH_OFF = XWZ_OFF + 9216000;
  const size_t XWR_OFF = XWH_OFF + 9216000;         // ends 97,654,784
  // overlays after scan:
  const size_t LQ_OFF  = M_OFF;                     // f32 [10240][780] (fits M+RM)
  const size_t AQ_OFF  = XWZ_OFF;                   // bf16 [10240][512] (XW dead post-scan)
  const size_t HQB_OFF = AQ_OFF + 10485760;
  const size_t PL_OFF  = HQB_OFF + 10485760;        // f32 [19968]
  const size_t AP_OFF  = M_OFF;                     // bf16 [19968][960] (M..weights dead)

  unsigned short* xb = (unsigned short*)(ws + XB_OFF);
  unsigned short* hb = (unsigned short*)(ws + HB_OFF);
  unsigned short* m_ = (unsigned short*)(ws + M_OFF);
  unsigned short* rm = (unsigned short*)(ws + RM_OFF);
  unsigned short* WzB = (unsigned short*)(ws + WZB_OFF);
  unsigned short* WhB = (unsigned short*)(ws + WHB_OFF);
  unsigned short* UrT = (unsigned short*)(ws + URT_OFF);
  unsigned short* WzTop = (unsigned short*)(ws + WZTOP_OFF);
  unsigned short* WhTop = (unsigned short*)(ws + WHTOP_OFF);
  unsigned short* WrT = (unsigned short*)(ws + WRT_OFF);
  unsigned short* WwT = (unsigned short*)(ws + WWT_OFF);
  unsigned short* UwT = (unsigned short*)(ws + UWT_OFF);
  unsigned short* WoT = (unsigned short*)(ws + WOT_OFF);
  unsigned short* XWz = (unsigned short*)(ws + XWZ_OFF);
  unsigned short* XWh = (unsigned short*)(ws + XWH_OFF);
  unsigned short* XWr = (unsigned short*)(ws + XWR_OFF);

  hipMemsetAsync(ws + M_OFF, 0, 2*18678784ull, stream);   // m, rm (incl sentinel+pads)
  hipMemsetAsync(d_out, 0, (size_t)out_size*sizeof(float), stream);

  k_gather_xb<<<2560, 256, 0, stream>>>(emb, wid, xb);

  // scan weights: bottom halves (K rows 450..899) + Ur; top halves for XW precompute
  k_wt<<<512, 256, 0, stream>>>(Wz + 450*450, Wz, 450, 450, 450, WzB, KS);
  k_wt<<<512, 256, 0, stream>>>(Wh + 450*450, Wh, 450, 450, 450, WhB, KS);
  k_wt<<<512, 256, 0, stream>>>(Ur, Ur, 450, 450, 450, UrT, KS);
  k_wt<<<512, 256, 0, stream>>>(Wz, Wz, 450, 450, 450, WzTop, KS);
  k_wt<<<512, 256, 0, stream>>>(Wh, Wh, 450, 450, 450, WhTop, KS);
  k_wt<<<512, 256, 0, stream>>>(Wr, Wr, 450, 450, 450, WrT, KS);
  k_wt<<<512, 256, 0, stream>>>(Ww, Ww, 506, 506, 450, WwT, 512);
  k_wt<<<512, 256, 0, stream>>>(Uw, Uw, 956, 956, 450, UwT, 960);
  k_wt<<<832, 256, 0, stream>>>(Wo, Wo, 450, 450, 780, WoT, 512);

  // XW precompute (bias folded): XWz = xb@WzTop + bz, etc.  [10240][450] bf16
  k_head_mfma<<<dim3(8,160), 256, 0, stream>>>(xb, WzTop, KS, bz, H_, 0, nullptr, 0, XWz, H_);
  k_head_mfma<<<dim3(8,160), 256, 0, stream>>>(xb, WhTop, KS, bh, H_, 0, nullptr, 0, XWh, H_);
  k_head_mfma<<<dim3(8,160), 256, 0, stream>>>(xb, WrT,   KS, br, H_, 0, nullptr, 0, XWr, H_);

  // ---- tree-owned fused scan: 64 blocks x 8 trees, no cross-block deps ----
  ScanP sp;
  sp.WzB = WzB; sp.WhB = WhB; sp.UrT = UrT;
  sp.XWz = XWz; sp.XWh = XWh; sp.XWr = XWr;
  sp.edge_src = edge_src; sp.edge_dst = edge_dst; sp.edge_pred = edge_pred;
  sp.node_in = node_in; sp.step_eid = step_eid; sp.step_v = step_v;
  sp.m = m_; sp.rm = rm; sp.hb = hb;
  sp.P = P; sp.Dn = Dn;
  k_scan_tree<<<64, 1024, 0, stream>>>(sp);

  // ---- q head ----
  unsigned short* Aq  = (unsigned short*)(ws + AQ_OFF);
  float* logitsq      = (float*)(ws + LQ_OFF);
  unsigned short* hqb = (unsigned short*)(ws + HQB_OFF);
  float* plog         = (float*)(ws + PL_OFF);
  hipMemsetAsync(plog, 0, (size_t)NPROWS*4, stream);

  k_build_Aq<<<640, 256, 0, stream>>>(hb, tree_vec, q_rows, Aq, nq);
  k_head_mfma<<<dim3(8, nq/64), 256, 0, stream>>>(Aq, WwT, 512, bw, H_, 1,
      nullptr, 0, hqb, 512);
  k_head_mfma<<<dim3(13, nq/64), 256, 0, stream>>>(hqb, WoT, 512, bo, V_, 0,
      logitsq, V_, nullptr, 0);
  k_qreduce2<<<320, 256, 0, stream>>>(logitsq, q_tgt, nq, (float*)d_out);

  // ---- p head ----
  unsigned short* Ap = (unsigned short*)(ws + AP_OFF);
  k_build_Ap<<<1248, 256, 0, stream>>>(hb, xb, tree_vec, root_ids, step_v, Ap);
  k_head_p<<<dim3(8, NPROWS/64), 256, 0, stream>>>(Ap, UwT, bu, Us, plog);
  k_pfinal<<<78, 256, 0, stream>>>(plog, bs, p_tgt, (float*)d_out);
}